// Round 5
// baseline (1059.001 us; speedup 1.0000x reference)
//
#include <hip/hip_runtime.h>
#include <hip/hip_fp16.h>

#define NN 100000
#define NE 3200000
#define NB 391          // coarse buckets of 256 nodes (dst >> 8)
#define NBLK 512        // edge-partition blocks for bin build
#define EPB 6250        // edges per block (NBLK * EPB == NE)
// dims: IN=128, HID=128, INT=512, OUT=3
// fp32 tensors on device; edge_index dtype probed per-block (int32/int64); fp32 out.
// Numerics: fp16 intermediates (dinv-prescaled) + single-pass fp16 weights; MFMA f16,
// fp32 acc (comparison floor measured at 1.2207e-4 = 2^-13).
// Round 13 (FAILED 129.5us): tail32 kb-outer, 8 live ntiles -> occ 2 blocks/CU.
// Round 14 (FAILED 149us): 2x4 ntile passes -> scratch spill. tail32 stays in r12
//   form: 2 live acc tiles + occupancy 4; conflicts hidden by TLP.
// Round 15: agg 8-deep batches: NEUTRAL -> agg is L3-BW-bound, not latency-bound.
// Round 16 (compile fail: nontemporal builtin needs clang vector, not HIP uint4).
// Round 17: same XCD-sliced aggregation, store via ext_vector alias. Gather
//   sources (xh, gemm C-out) chunk-major [8][NN][32B]; agg chunk = blockIdx.x&7
//   rides round-robin blockIdx->XCD so each XCD gathers from a 3.2MB slice
//   resident in its 4MB L2 (was 25.6MB from L3). csr reads + agg out writes
//   nontemporal. Agg output row-major: gemm A-read and tail32 untouched.

typedef unsigned int uint32;
typedef unsigned short u16;
typedef long long ll64;
typedef __attribute__((ext_vector_type(8))) _Float16 half8;
typedef __attribute__((ext_vector_type(4))) float f32x4;
typedef __attribute__((ext_vector_type(4))) uint32 nt4;  // clang vector for nontemporal

__device__ inline float2 h2f2(uint32 u) {
  __half2 h = *reinterpret_cast<__half2*>(&u);
  return __half22float2(h);
}
__device__ inline uint32 f2h2(float x, float y) {
  return (uint32)__half_as_ushort(__float2half(x)) |
         ((uint32)__half_as_ushort(__float2half(y)) << 16);
}
__device__ inline int edge_at(const void* ei, int is64, ll64 idx) {
  return is64 ? (int)((const ll64*)ei)[idx] : ((const int*)ei)[idx];
}
__device__ inline int detect64(const int* ei32) {
  int acc = 0;
#pragma unroll
  for (int k = 1; k < 32; k += 2) acc |= ei32[k];
  return (acc == 0) ? 1 : 0;
}

// ---- CSR build, 2-level counting sort ----
__global__ __launch_bounds__(256) void k_binB(const void* __restrict__ ei,
                                              int* __restrict__ tbl) {
  __shared__ int h[NB];
  __shared__ int sIs64;
  int k = blockIdx.x, tid = threadIdx.x;
  for (int i = tid; i < NB; i += 256) h[i] = 0;
  if (tid == 0) sIs64 = detect64((const int*)ei);
  __syncthreads();
  int is64 = sIs64;
  ll64 beg = (ll64)k * EPB, end = beg + EPB;
  for (ll64 i = beg + tid; i < end; i += 256)
    atomicAdd(&h[edge_at(ei, is64, (ll64)NE + i) >> 8], 1);
  __syncthreads();
  for (int i = tid; i < NB; i += 256) tbl[k * NB + i] = h[i];
}
__global__ __launch_bounds__(512) void k_binC1(int* __restrict__ tbl,
                                               int* __restrict__ total) {
  __shared__ int sd[NBLK];
  int b = blockIdx.x, tid = threadIdx.x;
  int v = tbl[tid * NB + b];
  sd[tid] = v;
  __syncthreads();
  for (int off = 1; off < NBLK; off <<= 1) {
    int t = (tid >= off) ? sd[tid - off] : 0;
    __syncthreads();
    sd[tid] += t;
    __syncthreads();
  }
  tbl[tid * NB + b] = sd[tid] - v;
  if (tid == NBLK - 1) total[b] = sd[NBLK - 1];
}
__global__ __launch_bounds__(512) void k_binC2(const int* __restrict__ total,
                                               int* __restrict__ bbase,
                                               int* __restrict__ offs) {
  __shared__ int sd[512];
  int tid = threadIdx.x;
  int v = (tid < NB) ? total[tid] : 0;
  sd[tid] = v;
  __syncthreads();
  for (int off = 1; off < 512; off <<= 1) {
    int t = (tid >= off) ? sd[tid - off] : 0;
    __syncthreads();
    sd[tid] += t;
    __syncthreads();
  }
  if (tid < NB) bbase[tid] = sd[tid] - v;
  if (tid == 0) offs[NN] = NE;
}
__global__ __launch_bounds__(256) void k_binD(const void* __restrict__ ei,
                                              const int* __restrict__ tbl,
                                              const int* __restrict__ bbase,
                                              uint32* __restrict__ binned) {
  __shared__ int lb[NB];
  __shared__ int lc[NB];
  __shared__ int sIs64;
  int k = blockIdx.x, tid = threadIdx.x;
  for (int i = tid; i < NB; i += 256) {
    lb[i] = tbl[k * NB + i] + bbase[i];
    lc[i] = 0;
  }
  if (tid == 0) sIs64 = detect64((const int*)ei);
  __syncthreads();
  int is64 = sIs64;
  ll64 beg = (ll64)k * EPB, end = beg + EPB;
  for (ll64 i = beg + tid; i < end; i += 256) {
    int s = edge_at(ei, is64, i);
    int d = edge_at(ei, is64, (ll64)NE + i);
    int b = d >> 8;
    int r = atomicAdd(&lc[b], 1);
    binned[lb[b] + r] = (uint32)s | ((uint32)(d & 255) << 24);
  }
}
__global__ __launch_bounds__(256) void k_binE(const uint32* __restrict__ binned,
                                              const int* __restrict__ bbase,
                                              const int* __restrict__ total,
                                              int* __restrict__ offs,
                                              float* __restrict__ dinv,
                                              int* __restrict__ csr) {
  __shared__ int cnt[256], pref[256], fil[256];
  int b = blockIdx.x, tid = threadIdx.x;
  cnt[tid] = 0;
  fil[tid] = 0;
  __syncthreads();
  int base = bbase[b], tot = total[b];
  for (int i = tid; i < tot; i += 256) atomicAdd(&cnt[binned[base + i] >> 24], 1);
  __syncthreads();
  int v = cnt[tid];
  pref[tid] = v;
  __syncthreads();
  for (int off = 1; off < 256; off <<= 1) {
    int t = (tid >= off) ? pref[tid - off] : 0;
    __syncthreads();
    pref[tid] += t;
    __syncthreads();
  }
  int myoff = pref[tid] - v;  // exclusive
  pref[tid] = myoff;
  int node = b * 256 + tid;
  if (node < NN) {
    offs[node] = base + myoff;
    dinv[node] = rsqrtf((float)(v + 1));  // +1: self-loop
  }
  __syncthreads();
  for (int i = tid; i < tot; i += 256) {
    uint32 w = binned[base + i];
    int dl = w >> 24;
    int r = atomicAdd(&fil[dl], 1);
    csr[base + pref[dl] + r] = (int)(w & 0xFFFFFFu);
  }
}

// ---- weight pack (fp16 B-fragment order) + x -> dinv-prescaled fp16 ----
// xh is written CHUNK-MAJOR: [chunk=dim>>4][node][16 dims] (32B per node per chunk)
__device__ inline void packOne(const float* __restrict__ W, u16* __restrict__ ph,
                               int K, int N, int t) {
  int j = t & 7, lane = (t >> 3) & 63, tl = t >> 9;
  int kbn = K >> 5;
  int kb = tl % kbn, ntile = tl / kbn;
  int k = kb * 32 + (lane >> 4) * 8 + j;
  int n2 = ntile * 16 + (lane & 15);
  ph[t] = __half_as_ushort(__float2half(W[k * N + n2]));
}
__global__ void k_packhalf(const float* W1, const float* W2, const float* W3,
                           const float* Wi, u16* p1, u16* p2, u16* p3, u16* pi,
                           const float4* __restrict__ x, ushort4* __restrict__ xh,
                           const float* __restrict__ dinv) {
  int t = blockIdx.x * blockDim.x + threadIdx.x;
  if (t < 16384) packOne(W1, p1, 128, 128, t);
  else if (t < 32768) packOne(W2, p2, 128, 128, t - 16384);
  else if (t < 98304) packOne(W3, p3, 128, 512, t - 32768);
  else if (t < 360448) packOne(Wi, pi, 512, 512, t - 98304);
  else {
    int i = t - 360448;
    if (i < NN * 32) {
      float4 v = x[i];
      float sc = dinv[i >> 5];  // 32 float4 per 128-dim row
      ushort4 o;
      o.x = __half_as_ushort(__float2half(v.x * sc));
      o.y = __half_as_ushort(__float2half(v.y * sc));
      o.z = __half_as_ushort(__float2half(v.z * sc));
      o.w = __half_as_ushort(__float2half(v.w * sc));
      int row = i >> 5, j = i & 31;  // j = float4 idx within row; chunk = j>>2
      xh[(ll64)(j >> 2) * (NN * 4) + row * 4 + (j & 3)] = o;
    }
  }
}

// ---- Aggregation: XCD-sliced. chunk = blockIdx.x & 7 (round-robin -> one XCD
// per chunk); gather source chunk-major so each XCD's 3.2MB slice is L2-resident.
// 2 lanes per node (32B = 16 dims); 32 nodes/wave; output ROW-major.
// csr reads + output stores nontemporal (don't evict the slice).
__global__ void k_agg(const uint32* __restrict__ xi, uint32* __restrict__ o,
                      const int* __restrict__ csr, const int* __restrict__ offs,
                      const float* __restrict__ dinv, int n) {
  int tid = threadIdx.x;
  int chunk = blockIdx.x & 7;
  int nb = blockIdx.x >> 3;
  int lane = tid & 63;
  int sub = lane & 1;           // which 16B half of the 32B chunk-slice
  int nloc = lane >> 1;         // 32 nodes per wave
  int node = nb * 128 + (tid >> 6) * 32 + nloc;
  if (node >= n) return;
  int beg = offs[node], end = offs[node + 1];
  const nt4* xv = (const nt4*)xi;
  ll64 cbase = (ll64)chunk * (NN * 2);  // 16B units per chunk region
  float acc[8] = {};
  int j = beg;
  for (; j + 7 < end; j += 8) {
    int s[8];
    nt4 r[8];
#pragma unroll
    for (int q = 0; q < 8; q++) s[q] = __builtin_nontemporal_load(&csr[j + q]);
#pragma unroll
    for (int q = 0; q < 8; q++) r[q] = xv[cbase + (ll64)s[q] * 2 + sub];
#pragma unroll
    for (int q = 0; q < 8; q++) {
      float2 p0 = h2f2(r[q].x), p1 = h2f2(r[q].y);
      float2 p2 = h2f2(r[q].z), p3 = h2f2(r[q].w);
      acc[0] += p0.x; acc[1] += p0.y; acc[2] += p1.x; acc[3] += p1.y;
      acc[4] += p2.x; acc[5] += p2.y; acc[6] += p3.x; acc[7] += p3.y;
    }
  }
  for (; j + 3 < end; j += 4) {
    int s[4];
    nt4 r[4];
#pragma unroll
    for (int q = 0; q < 4; q++) s[q] = __builtin_nontemporal_load(&csr[j + q]);
#pragma unroll
    for (int q = 0; q < 4; q++) r[q] = xv[cbase + (ll64)s[q] * 2 + sub];
#pragma unroll
    for (int q = 0; q < 4; q++) {
      float2 p0 = h2f2(r[q].x), p1 = h2f2(r[q].y);
      float2 p2 = h2f2(r[q].z), p3 = h2f2(r[q].w);
      acc[0] += p0.x; acc[1] += p0.y; acc[2] += p1.x; acc[3] += p1.y;
      acc[4] += p2.x; acc[5] += p2.y; acc[6] += p3.x; acc[7] += p3.y;
    }
  }
  for (; j < end; j++) {
    int s = __builtin_nontemporal_load(&csr[j]);
    nt4 r = xv[cbase + (ll64)s * 2 + sub];
    float2 p0 = h2f2(r.x), p1 = h2f2(r.y), p2 = h2f2(r.z), p3 = h2f2(r.w);
    acc[0] += p0.x; acc[1] += p0.y; acc[2] += p1.x; acc[3] += p1.y;
    acc[4] += p2.x; acc[5] += p2.y; acc[6] += p3.x; acc[7] += p3.y;
  }
  float di = dinv[node];
  nt4 sf = xv[cbase + (ll64)node * 2 + sub];
  float2 q0 = h2f2(sf.x), q1 = h2f2(sf.y), q2 = h2f2(sf.z), q3 = h2f2(sf.w);
  nt4 ov;
  ov.x = f2h2(di * (acc[0] + q0.x), di * (acc[1] + q0.y));
  ov.y = f2h2(di * (acc[2] + q1.x), di * (acc[3] + q1.y));
  ov.z = f2h2(di * (acc[4] + q2.x), di * (acc[5] + q2.y));
  ov.w = f2h2(di * (acc[6] + q3.x), di * (acc[7] + q3.y));
  // output row-major: row stride 16x16B; this lane's 16B at chunk*2+sub
  __builtin_nontemporal_store(ov, &((nt4*)o)[(ll64)node * 16 + chunk * 2 + sub]);
}

// -- MFMA GEMM: C = dinv[row]*relu(A@W + bias); A row-major, C CHUNK-MAJOR --
__global__ __launch_bounds__(256, 4) void k_gemm_mfma(
    const u16* __restrict__ A, const u16* __restrict__ Bp,
    const float* __restrict__ bias, const float* __restrict__ dscale,
    u16* __restrict__ Co, int M, int N, int K) {
  int wave = threadIdx.x >> 6, lane = threadIdx.x & 63;
  int quad = lane >> 4, l16 = lane & 15;
  int row0 = blockIdx.x * 64, col0 = blockIdx.y * 64;
  int m = row0 + wave * 16 + l16;
  int mc = (m < M) ? m : (M - 1);
  int kbn = K >> 5;
  f32x4 acc[4] = {{0,0,0,0},{0,0,0,0},{0,0,0,0},{0,0,0,0}};
  const half8* Ar = (const half8*)&A[(ll64)mc * K];
  half8 ac = Ar[quad];
  half8 an = ac;
  half8 bc_[4], bn_[4];
#pragma unroll
  for (int nt = 0; nt < 4; nt++)
    bc_[nt] = *(const half8*)&Bp[((ll64)(((col0 >> 4) + nt) * kbn) * 64 + lane) * 8];
  for (int kb = 0; kb < kbn; kb++) {
    int kn = kb + 1;
    if (kn < kbn) {
      an = Ar[kn * 4 + quad];
#pragma unroll
      for (int nt = 0; nt < 4; nt++)
        bn_[nt] = *(const half8*)&Bp[((ll64)(((col0 >> 4) + nt) * kbn + kn) * 64 + lane) * 8];
    }
#pragma unroll
    for (int nt = 0; nt < 4; nt++)
      acc[nt] = __builtin_amdgcn_mfma_f32_16x16x32_f16(ac, bc_[nt], acc[nt], 0, 0, 0);
    ac = an;
#pragma unroll
    for (int nt = 0; nt < 4; nt++) bc_[nt] = bn_[nt];
  }
  float ds[4];
#pragma unroll
  for (int r = 0; r < 4; r++) {
    int rr = row0 + wave * 16 + quad * 4 + r;
    ds[r] = dscale[(rr < M) ? rr : (M - 1)];
  }
#pragma unroll
  for (int nt = 0; nt < 4; nt++) {
    int cc = col0 + nt * 16 + l16;
    float bv = bias[cc];
    ll64 cmaj = (ll64)(cc >> 4) * ((ll64)M * 16);  // chunk region base (u16)
#pragma unroll
    for (int r = 0; r < 4; r++) {
      int rr = row0 + wave * 16 + quad * 4 + r;
      if (rr < M)
        Co[cmaj + (ll64)rr * 16 + l16] =
            __half_as_ushort(__float2half(fmaxf(acc[nt][r] + bv, 0.0f) * ds[r]));
    }
  }
}

// ---- Fused tail 32-row: h3 in LDS; out = relu(h3@Wi+bi)@Wc+bc; depth-3 B ring ----
// r12 form (verbatim): 2 live acc tiles, t-inner; occupancy 4 blocks/CU hides
// the Wi L2 stream + LDS conflicts. a3 (agg output) is ROW-major - untouched.
__global__ __launch_bounds__(256, 4) void k_tail32(
    const u16* __restrict__ a3, const u16* __restrict__ W3p,
    const float* __restrict__ b3, const u16* __restrict__ Wip,
    const float* __restrict__ bi, const float* __restrict__ Wc,
    const float* __restrict__ bc, float* __restrict__ out, int M) {
  __shared__ u16 h3s[32 * 512];     // 32 KB, col-octets xor-swizzled by row&7
  __shared__ float sRed[4][32][3];  // 1.5 KB
  int tid = threadIdx.x;
  int wave = tid >> 6, lane = tid & 63, quad = lane >> 4, l16 = lane & 15;
  int row0 = blockIdx.x * 32;  // NN % 32 == 0

  half8 af[2][4];
#pragma unroll
  for (int rt = 0; rt < 2; rt++) {
    const half8* Ar = (const half8*)&a3[(ll64)(row0 + rt * 16 + l16) * 128];
#pragma unroll
    for (int kb = 0; kb < 4; kb++) af[rt][kb] = Ar[kb * 4 + quad];
  }
  // ---- phase 1: 32x512 = a3[32x128] @ W3 into LDS; ring prefetch depth 3 ----
  {
    f32x4 acc0 = {0, 0, 0, 0}, acc1 = {0, 0, 0, 0};
    half8 bq[4];
#pragma unroll
    for (int p = 0; p < 3; p++)
      bq[p] = *(const half8*)&W3p[((ll64)(wave * 32 + p) * 64 + lane) * 8];
#pragma unroll 4
    for (int t = 0; t < 32; t++) {
      if (t + 3 < 32)
        bq[(t + 3) & 3] = *(const half8*)&W3p[((ll64)(wave * 32 + t + 3) * 64 + lane) * 8];
      half8 bcur = bq[t & 3];
      int kb = t & 3;
      acc0 = __builtin_amdgcn_mfma_f32_16x16x32_f16(af[0][kb], bcur, acc0, 0, 0, 0);
      acc1 = __builtin_amdgcn_mfma_f32_16x16x32_f16(af[1][kb], bcur, acc1, 0, 0, 0);
      if (kb == 3) {
        int nt = wave * 8 + (t >> 2);
        int col = nt * 16 + l16;
        float bv = b3[col];
#pragma unroll
        for (int r = 0; r < 4; r++) {
          int row0l = quad * 4 + r;
          float v0 = fmaxf(acc0[r] + bv, 0.0f);
          float v1 = fmaxf(acc1[r] + bv, 0.0f);
          int oct0 = (col >> 3) ^ (row0l & 7);
          h3s[row0l * 512 + oct0 * 8 + (col & 7)] = __half_as_ushort(__float2half(v0));
          int row1l = 16 + row0l;
          int oct1 = (col >> 3) ^ (row1l & 7);
          h3s[row1l * 512 + oct1 * 8 + (col & 7)] = __half_as_ushort(__float2half(v1));
        }
        acc0 = (f32x4){0, 0, 0, 0};
        acc1 = (f32x4){0, 0, 0, 0};
      }
    }
  }
  __syncthreads();

  // ---- phase 2: h3s @ Wi (K=512) + fold Wc; ring prefetch depth 3 ----
  float acc3[2][4][3] = {};
  {
    f32x4 acc0 = {0, 0, 0, 0}, acc1 = {0, 0, 0, 0};
    half8 bq[4];
#pragma unroll
    for (int p = 0; p < 3; p++)
      bq[p] = *(const half8*)&Wip[((ll64)(wave * 128 + p) * 64 + lane) * 8];
    int r0l = l16, r1l = 16 + l16;
    int sw0 = r0l & 7;
#pragma unroll 4
    for (int t = 0; t < 128; t++) {
      if (t + 3 < 128)
        bq[(t + 3) & 3] = *(const half8*)&Wip[((ll64)(wave * 128 + t + 3) * 64 + lane) * 8];
      half8 bcur = bq[t & 3];
      int kb = t & 15;
      int oct = ((kb * 4 + quad) ^ sw0);
      half8 a0 = *(const half8*)&h3s[r0l * 512 + oct * 8];
      half8 a1 = *(const half8*)&h3s[r1l * 512 + oct * 8];
      acc0 = __builtin_amdgcn_mfma_f32_16x16x32_f16(a0, bcur, acc0, 0, 0, 0);
      acc1 = __builtin_amdgcn_mfma_f32_16x16x32_f16(a1, bcur, acc1, 0, 0, 0);
      if (kb == 15) {
        int nt = wave * 8 + (t >> 4);
        int col = nt * 16 + l16;
        float bv = bi[col];
        float w0 = Wc[col * 3 + 0], w1 = Wc[col * 3 + 1], w2 = Wc[col * 3 + 2];
#pragma unroll
        for (int r = 0; r < 4; r++) {
          float v0 = fmaxf(acc0[r] + bv, 0.0f);
          float v1 = fmaxf(acc1[r] + bv, 0.0f);
          acc3[0][r][0] += v0 * w0; acc3[0][r][1] += v0 * w1; acc3[0][r][2] += v0 * w2;
          acc3[1][r][0] += v1 * w0; acc3[1][r][1] += v1 * w1; acc3[1][r][2] += v1 * w2;
        }
        acc0 = (f32x4){0, 0, 0, 0};
        acc1 = (f32x4){0, 0, 0, 0};
      }
    }
  }
#pragma unroll
  for (int rt = 0; rt < 2; rt++)
#pragma unroll
    for (int r = 0; r < 4; r++)
#pragma unroll
      for (int c = 0; c < 3; c++) {
        float v = acc3[rt][r][c];
        v += __shfl_xor(v, 1);
        v += __shfl_xor(v, 2);
        v += __shfl_xor(v, 4);
        v += __shfl_xor(v, 8);
        acc3[rt][r][c] = v;
      }
  if (l16 == 0) {
#pragma unroll
    for (int rt = 0; rt < 2; rt++)
#pragma unroll
      for (int r = 0; r < 4; r++)
#pragma unroll
        for (int c = 0; c < 3; c++)
          sRed[wave][rt * 16 + quad * 4 + r][c] = acc3[rt][r][c];
  }
  __syncthreads();
  if (tid < 96) {
    int row = tid / 3, c = tid % 3;
    out[(ll64)(row0 + row) * 3 + c] = sRed[0][row][c] + sRed[1][row][c] +
                                      sRed[2][row][c] + sRed[3][row][c] + bc[c];
  }
}

// ---------------- launcher ----------------
extern "C" void kernel_launch(void* const* d_in, const int* in_sizes, int n_in,
                              void* d_out, int out_size, void* d_ws, size_t ws_size,
                              hipStream_t stream) {
  const float* x  = (const float*)d_in[0];
  const void*  ei = d_in[1];
  const float* W1 = (const float*)d_in[2];
  const float* b1 = (const float*)d_in[3];
  const float* W2 = (const float*)d_in[4];
  const float* b2 = (const float*)d_in[5];
  const float* W3 = (const float*)d_in[6];
  const float* b3 = (const float*)d_in[7];
  const float* Wi = (const float*)d_in[8];
  const float* bi = (const float*)d_in[9];
  const float* Wc = (const float*)d_in[10];
  const float* bc = (const float*)d_in[11];
  float* out = (float*)d_out;

  char* ws = (char*)d_ws;
  const ll64 KB = 1ll << 10, MB = 1ll << 20;
  float* dinv  = (float*)(ws + 0);                 // 400 KB
  int*   offs  = (int*)(ws + 512 * KB);            // 400 KB (NN+1)
  int*   total = (int*)(ws + 1 * MB + 64 * KB);    // 1.6 KB
  int*   bbase = (int*)(ws + 1 * MB + 128 * KB);   // 1.6 KB
  int*   tbl   = (int*)(ws + 1 * MB + 192 * KB);   // 800 KB -> ends ~2 MB
  uint32* binned = (uint32*)(ws + 2 * MB);         // 12.8 MB -> 14.8
  int*   csr   = (int*)(ws + 15 * MB);             // 12.8 MB -> 27.8
  u16* pW1 = (u16*)(ws + 28 * MB);                 // 32 KB
  u16* pW2 = (u16*)(ws + 28 * MB + 64 * KB);       // 32 KB
  u16* pW3 = (u16*)(ws + 28 * MB + 128 * KB);      // 128 KB
  u16* pWi = (u16*)(ws + 28 * MB + 512 * KB);      // 512 KB
  u16* xh   = (u16*)(ws + 29 * MB);                // 25.6 MB -> 54.6 (chunk-major)
  u16* bufA = (u16*)(ws + 55 * MB);                // 25.6 MB -> 80.6 (row-major)
  u16* bufB = (u16*)(ws + 81 * MB);                // 25.6 MB -> 106.6 (chunk-major)

  const int TB = 256;
  k_binB<<<NBLK, TB, 0, stream>>>(ei, tbl);
  k_binC1<<<NB, NBLK, 0, stream>>>(tbl, total);
  k_binC2<<<1, 512, 0, stream>>>(total, bbase, offs);
  k_binD<<<NBLK, TB, 0, stream>>>(ei, tbl, bbase, binned);
  k_binE<<<NB, TB, 0, stream>>>(binned, bbase, total, offs, dinv, csr);
  // pack weights + convert x to dinv-prescaled fp16 (chunk-major; after binE)
  k_packhalf<<<(360448 + NN * 32 + TB - 1) / TB, TB, 0, stream>>>(
      W1, W2, W3, Wi, pW1, pW2, pW3, pWi, (const float4*)x, (ushort4*)xh, dinv);

  const int MBk = (NN + 63) / 64;  // 1563
  int aggBlocks = 8 * ((NN + 127) / 128);  // 8 chunks x 782 node-blocks
  dim3 g128(MBk, 2);

  // layer 1
  k_agg<<<aggBlocks, TB, 0, stream>>>((const uint32*)xh, (uint32*)bufA, csr, offs, dinv, NN);
  k_gemm_mfma<<<g128, TB, 0, stream>>>(bufA, pW1, b1, dinv, bufB, NN, 128, 128);
  // layer 2
  k_agg<<<aggBlocks, TB, 0, stream>>>((const uint32*)bufB, (uint32*)bufA, csr, offs, dinv, NN);
  k_gemm_mfma<<<g128, TB, 0, stream>>>(bufA, pW2, b2, dinv, bufB, NN, 128, 128);
  // layer 3 aggregation, then fused GEMM512 + MLP head
  k_agg<<<aggBlocks, TB, 0, stream>>>((const uint32*)bufB, (uint32*)bufA, csr, offs, dinv, NN);
  k_tail32<<<NN / 32, TB, 0, stream>>>(bufA, pW3, b3, pWi, bi, Wc, bc, out, NN);
}

// Round 6
// 697.033 us; speedup vs baseline: 1.5193x; 1.5193x over previous
//
#include <hip/hip_runtime.h>
#include <hip/hip_fp16.h>

#define NN 100000
#define NE 3200000
#define NB 391          // coarse buckets of 256 nodes (dst >> 8)
#define NBLK 512        // edge-partition blocks for bin build
#define EPB 6250        // edges per block (NBLK * EPB == NE)
// dims: IN=128, HID=128, INT=512, OUT=3
// fp32 tensors on device; edge_index dtype probed per-block (int32/int64); fp32 out.
// Numerics: fp16 intermediates (dinv-prescaled) + single-pass fp16 weights; MFMA f16,
// fp32 acc (comparison floor measured at 1.2207e-4 = 2^-13).
// Round 13 (FAILED 129.5us): tail32 kb-outer, 8 live ntiles -> occ 2 blocks/CU.
// Round 14 (FAILED 149us): 2x4 ntile passes -> scratch spill. tail32 stays in r12
//   form: 2 live acc tiles + occupancy 4; conflicts hidden by TLP.
// Round 15: agg 8-deep batches: NEUTRAL -> agg is L3-BW-bound, not latency-bound.
// Round 17 (FAILED 1059us): XCD-sliced chunk-major agg. FETCH 256MB/agg dispatch
//   (10x the gather buffer) -> per-XCD L2 slices don't stay resident; 32B-granule
//   requests overfetch 64B lines; 8x csr re-reads. REVERTED to r15 row-major agg:
//   4 contiguous 256B rows per wave gather, ~9TB/s effective L3 = within ~5% of
//   the structural floor (depth test r15 proved BW-bound).

typedef unsigned int uint32;
typedef unsigned short u16;
typedef long long ll64;
typedef __attribute__((ext_vector_type(8))) _Float16 half8;
typedef __attribute__((ext_vector_type(4))) float f32x4;

__device__ inline float2 h2f2(uint32 u) {
  __half2 h = *reinterpret_cast<__half2*>(&u);
  return __half22float2(h);
}
__device__ inline uint32 f2h2(float x, float y) {
  return (uint32)__half_as_ushort(__float2half(x)) |
         ((uint32)__half_as_ushort(__float2half(y)) << 16);
}
__device__ inline int edge_at(const void* ei, int is64, ll64 idx) {
  return is64 ? (int)((const ll64*)ei)[idx] : ((const int*)ei)[idx];
}
__device__ inline int detect64(const int* ei32) {
  int acc = 0;
#pragma unroll
  for (int k = 1; k < 32; k += 2) acc |= ei32[k];
  return (acc == 0) ? 1 : 0;
}

// ---- CSR build, 2-level counting sort ----
__global__ __launch_bounds__(256) void k_binB(const void* __restrict__ ei,
                                              int* __restrict__ tbl) {
  __shared__ int h[NB];
  __shared__ int sIs64;
  int k = blockIdx.x, tid = threadIdx.x;
  for (int i = tid; i < NB; i += 256) h[i] = 0;
  if (tid == 0) sIs64 = detect64((const int*)ei);
  __syncthreads();
  int is64 = sIs64;
  ll64 beg = (ll64)k * EPB, end = beg + EPB;
  for (ll64 i = beg + tid; i < end; i += 256)
    atomicAdd(&h[edge_at(ei, is64, (ll64)NE + i) >> 8], 1);
  __syncthreads();
  for (int i = tid; i < NB; i += 256) tbl[k * NB + i] = h[i];
}
__global__ __launch_bounds__(512) void k_binC1(int* __restrict__ tbl,
                                               int* __restrict__ total) {
  __shared__ int sd[NBLK];
  int b = blockIdx.x, tid = threadIdx.x;
  int v = tbl[tid * NB + b];
  sd[tid] = v;
  __syncthreads();
  for (int off = 1; off < NBLK; off <<= 1) {
    int t = (tid >= off) ? sd[tid - off] : 0;
    __syncthreads();
    sd[tid] += t;
    __syncthreads();
  }
  tbl[tid * NB + b] = sd[tid] - v;
  if (tid == NBLK - 1) total[b] = sd[NBLK - 1];
}
__global__ __launch_bounds__(512) void k_binC2(const int* __restrict__ total,
                                               int* __restrict__ bbase,
                                               int* __restrict__ offs) {
  __shared__ int sd[512];
  int tid = threadIdx.x;
  int v = (tid < NB) ? total[tid] : 0;
  sd[tid] = v;
  __syncthreads();
  for (int off = 1; off < 512; off <<= 1) {
    int t = (tid >= off) ? sd[tid - off] : 0;
    __syncthreads();
    sd[tid] += t;
    __syncthreads();
  }
  if (tid < NB) bbase[tid] = sd[tid] - v;
  if (tid == 0) offs[NN] = NE;
}
__global__ __launch_bounds__(256) void k_binD(const void* __restrict__ ei,
                                              const int* __restrict__ tbl,
                                              const int* __restrict__ bbase,
                                              uint32* __restrict__ binned) {
  __shared__ int lb[NB];
  __shared__ int lc[NB];
  __shared__ int sIs64;
  int k = blockIdx.x, tid = threadIdx.x;
  for (int i = tid; i < NB; i += 256) {
    lb[i] = tbl[k * NB + i] + bbase[i];
    lc[i] = 0;
  }
  if (tid == 0) sIs64 = detect64((const int*)ei);
  __syncthreads();
  int is64 = sIs64;
  ll64 beg = (ll64)k * EPB, end = beg + EPB;
  for (ll64 i = beg + tid; i < end; i += 256) {
    int s = edge_at(ei, is64, i);
    int d = edge_at(ei, is64, (ll64)NE + i);
    int b = d >> 8;
    int r = atomicAdd(&lc[b], 1);
    binned[lb[b] + r] = (uint32)s | ((uint32)(d & 255) << 24);
  }
}
__global__ __launch_bounds__(256) void k_binE(const uint32* __restrict__ binned,
                                              const int* __restrict__ bbase,
                                              const int* __restrict__ total,
                                              int* __restrict__ offs,
                                              float* __restrict__ dinv,
                                              int* __restrict__ csr) {
  __shared__ int cnt[256], pref[256], fil[256];
  int b = blockIdx.x, tid = threadIdx.x;
  cnt[tid] = 0;
  fil[tid] = 0;
  __syncthreads();
  int base = bbase[b], tot = total[b];
  for (int i = tid; i < tot; i += 256) atomicAdd(&cnt[binned[base + i] >> 24], 1);
  __syncthreads();
  int v = cnt[tid];
  pref[tid] = v;
  __syncthreads();
  for (int off = 1; off < 256; off <<= 1) {
    int t = (tid >= off) ? pref[tid - off] : 0;
    __syncthreads();
    pref[tid] += t;
    __syncthreads();
  }
  int myoff = pref[tid] - v;  // exclusive
  pref[tid] = myoff;
  int node = b * 256 + tid;
  if (node < NN) {
    offs[node] = base + myoff;
    dinv[node] = rsqrtf((float)(v + 1));  // +1: self-loop
  }
  __syncthreads();
  for (int i = tid; i < tot; i += 256) {
    uint32 w = binned[base + i];
    int dl = w >> 24;
    int r = atomicAdd(&fil[dl], 1);
    csr[base + pref[dl] + r] = (int)(w & 0xFFFFFFu);
  }
}

// ---- weight pack (fp16 B-fragment order) + x -> dinv-prescaled fp16 ----
__device__ inline void packOne(const float* __restrict__ W, u16* __restrict__ ph,
                               int K, int N, int t) {
  int j = t & 7, lane = (t >> 3) & 63, tl = t >> 9;
  int kbn = K >> 5;
  int kb = tl % kbn, ntile = tl / kbn;
  int k = kb * 32 + (lane >> 4) * 8 + j;
  int n2 = ntile * 16 + (lane & 15);
  ph[t] = __half_as_ushort(__float2half(W[k * N + n2]));
}
__global__ void k_packhalf(const float* W1, const float* W2, const float* W3,
                           const float* Wi, u16* p1, u16* p2, u16* p3, u16* pi,
                           const float4* __restrict__ x, ushort4* __restrict__ xh,
                           const float* __restrict__ dinv) {
  int t = blockIdx.x * blockDim.x + threadIdx.x;
  if (t < 16384) packOne(W1, p1, 128, 128, t);
  else if (t < 32768) packOne(W2, p2, 128, 128, t - 16384);
  else if (t < 98304) packOne(W3, p3, 128, 512, t - 32768);
  else if (t < 360448) packOne(Wi, pi, 512, 512, t - 98304);
  else {
    int i = t - 360448;
    if (i < NN * 32) {
      float4 v = x[i];
      float sc = dinv[i >> 5];  // 32 float4 per 128-dim row
      ushort4 o;
      o.x = __half_as_ushort(__float2half(v.x * sc));
      o.y = __half_as_ushort(__float2half(v.y * sc));
      o.z = __half_as_ushort(__float2half(v.z * sc));
      o.w = __half_as_ushort(__float2half(v.w * sc));
      xh[i] = o;
    }
  }
}

// ---- Aggregation: 4 nodes/wave (16 lanes per node, uint4 = 16B/lane gathers) ----
// input rows carry dinv[s]; out[i] = dinv[i]*(sum_s x'[s] + x'[i])
__global__ void k_agg(const uint32* __restrict__ xi, uint32* __restrict__ o,
                      const int* __restrict__ csr, const int* __restrict__ offs,
                      const float* __restrict__ dinv, int n) {
  int tid = threadIdx.x;
  int lane = tid & 63;
  int sub = lane >> 4, fl = lane & 15;
  int node = blockIdx.x * 16 + (tid >> 6) * 4 + sub;
  if (node >= n) return;
  int beg = offs[node], end = offs[node + 1];
  const uint4* xv = (const uint4*)xi;  // 16 uint4 per 128-dim row
  float acc[8] = {};
  int j = beg;
  for (; j + 7 < end; j += 8) {
    int s[8];
    uint4 r[8];
#pragma unroll
    for (int q = 0; q < 8; q++) s[q] = csr[j + q];
#pragma unroll
    for (int q = 0; q < 8; q++) r[q] = xv[(ll64)s[q] * 16 + fl];
#pragma unroll
    for (int q = 0; q < 8; q++) {
      float2 p0 = h2f2(r[q].x), p1 = h2f2(r[q].y);
      float2 p2 = h2f2(r[q].z), p3 = h2f2(r[q].w);
      acc[0] += p0.x; acc[1] += p0.y; acc[2] += p1.x; acc[3] += p1.y;
      acc[4] += p2.x; acc[5] += p2.y; acc[6] += p3.x; acc[7] += p3.y;
    }
  }
  for (; j + 3 < end; j += 4) {
    int s[4];
    uint4 r[4];
#pragma unroll
    for (int q = 0; q < 4; q++) s[q] = csr[j + q];
#pragma unroll
    for (int q = 0; q < 4; q++) r[q] = xv[(ll64)s[q] * 16 + fl];
#pragma unroll
    for (int q = 0; q < 4; q++) {
      float2 p0 = h2f2(r[q].x), p1 = h2f2(r[q].y);
      float2 p2 = h2f2(r[q].z), p3 = h2f2(r[q].w);
      acc[0] += p0.x; acc[1] += p0.y; acc[2] += p1.x; acc[3] += p1.y;
      acc[4] += p2.x; acc[5] += p2.y; acc[6] += p3.x; acc[7] += p3.y;
    }
  }
  for (; j < end; j++) {
    uint4 r = xv[(ll64)csr[j] * 16 + fl];
    float2 p0 = h2f2(r.x), p1 = h2f2(r.y), p2 = h2f2(r.z), p3 = h2f2(r.w);
    acc[0] += p0.x; acc[1] += p0.y; acc[2] += p1.x; acc[3] += p1.y;
    acc[4] += p2.x; acc[5] += p2.y; acc[6] += p3.x; acc[7] += p3.y;
  }
  float di = dinv[node];
  uint4 sf = xv[(ll64)node * 16 + fl];
  float2 q0 = h2f2(sf.x), q1 = h2f2(sf.y), q2 = h2f2(sf.z), q3 = h2f2(sf.w);
  uint4 ov;
  ov.x = f2h2(di * (acc[0] + q0.x), di * (acc[1] + q0.y));
  ov.y = f2h2(di * (acc[2] + q1.x), di * (acc[3] + q1.y));
  ov.z = f2h2(di * (acc[4] + q2.x), di * (acc[5] + q2.y));
  ov.w = f2h2(di * (acc[6] + q3.x), di * (acc[7] + q3.y));
  ((uint4*)o)[(ll64)node * 16 + fl] = ov;
}

// -- MFMA GEMM: C = dinv[row]*relu(A@W + bias) (pre-scaled for next agg); reg dbuf --
__global__ __launch_bounds__(256, 4) void k_gemm_mfma(
    const u16* __restrict__ A, const u16* __restrict__ Bp,
    const float* __restrict__ bias, const float* __restrict__ dscale,
    u16* __restrict__ Co, int M, int N, int K) {
  int wave = threadIdx.x >> 6, lane = threadIdx.x & 63;
  int quad = lane >> 4, l16 = lane & 15;
  int row0 = blockIdx.x * 64, col0 = blockIdx.y * 64;
  int m = row0 + wave * 16 + l16;
  int mc = (m < M) ? m : (M - 1);
  int kbn = K >> 5;
  f32x4 acc[4] = {{0,0,0,0},{0,0,0,0},{0,0,0,0},{0,0,0,0}};
  const half8* Ar = (const half8*)&A[(ll64)mc * K];
  half8 ac = Ar[quad];
  half8 an = ac;
  half8 bc_[4], bn_[4];
#pragma unroll
  for (int nt = 0; nt < 4; nt++)
    bc_[nt] = *(const half8*)&Bp[((ll64)(((col0 >> 4) + nt) * kbn) * 64 + lane) * 8];
  for (int kb = 0; kb < kbn; kb++) {
    int kn = kb + 1;
    if (kn < kbn) {
      an = Ar[kn * 4 + quad];
#pragma unroll
      for (int nt = 0; nt < 4; nt++)
        bn_[nt] = *(const half8*)&Bp[((ll64)(((col0 >> 4) + nt) * kbn + kn) * 64 + lane) * 8];
    }
#pragma unroll
    for (int nt = 0; nt < 4; nt++)
      acc[nt] = __builtin_amdgcn_mfma_f32_16x16x32_f16(ac, bc_[nt], acc[nt], 0, 0, 0);
    ac = an;
#pragma unroll
    for (int nt = 0; nt < 4; nt++) bc_[nt] = bn_[nt];
  }
  float ds[4];
#pragma unroll
  for (int r = 0; r < 4; r++) {
    int rr = row0 + wave * 16 + quad * 4 + r;
    ds[r] = dscale[(rr < M) ? rr : (M - 1)];
  }
#pragma unroll
  for (int nt = 0; nt < 4; nt++) {
    int cc = col0 + nt * 16 + l16;
    float bv = bias[cc];
#pragma unroll
    for (int r = 0; r < 4; r++) {
      int rr = row0 + wave * 16 + quad * 4 + r;
      if (rr < M)
        Co[(ll64)rr * N + cc] =
            __half_as_ushort(__float2half(fmaxf(acc[nt][r] + bv, 0.0f) * ds[r]));
    }
  }
}

// ---- Fused tail 32-row: h3 in LDS; out = relu(h3@Wi+bi)@Wc+bc; depth-3 B ring ----
// r12 form (verbatim): 2 live acc tiles, t-inner; occupancy 4 blocks/CU hides
// the Wi L2 stream + LDS conflicts. r13/r14 proved deeper acc tiling loses to
// either occupancy (140 regs -> 2 blk/CU) or spill (under the (256,4) cap).
__global__ __launch_bounds__(256, 4) void k_tail32(
    const u16* __restrict__ a3, const u16* __restrict__ W3p,
    const float* __restrict__ b3, const u16* __restrict__ Wip,
    const float* __restrict__ bi, const float* __restrict__ Wc,
    const float* __restrict__ bc, float* __restrict__ out, int M) {
  __shared__ u16 h3s[32 * 512];     // 32 KB, col-octets xor-swizzled by row&7
  __shared__ float sRed[4][32][3];  // 1.5 KB
  int tid = threadIdx.x;
  int wave = tid >> 6, lane = tid & 63, quad = lane >> 4, l16 = lane & 15;
  int row0 = blockIdx.x * 32;  // NN % 32 == 0

  half8 af[2][4];
#pragma unroll
  for (int rt = 0; rt < 2; rt++) {
    const half8* Ar = (const half8*)&a3[(ll64)(row0 + rt * 16 + l16) * 128];
#pragma unroll
    for (int kb = 0; kb < 4; kb++) af[rt][kb] = Ar[kb * 4 + quad];
  }
  // ---- phase 1: 32x512 = a3[32x128] @ W3 into LDS; ring prefetch depth 3 ----
  {
    f32x4 acc0 = {0, 0, 0, 0}, acc1 = {0, 0, 0, 0};
    half8 bq[4];
#pragma unroll
    for (int p = 0; p < 3; p++)
      bq[p] = *(const half8*)&W3p[((ll64)(wave * 32 + p) * 64 + lane) * 8];
#pragma unroll 4
    for (int t = 0; t < 32; t++) {
      if (t + 3 < 32)
        bq[(t + 3) & 3] = *(const half8*)&W3p[((ll64)(wave * 32 + t + 3) * 64 + lane) * 8];
      half8 bcur = bq[t & 3];
      int kb = t & 3;
      acc0 = __builtin_amdgcn_mfma_f32_16x16x32_f16(af[0][kb], bcur, acc0, 0, 0, 0);
      acc1 = __builtin_amdgcn_mfma_f32_16x16x32_f16(af[1][kb], bcur, acc1, 0, 0, 0);
      if (kb == 3) {
        int nt = wave * 8 + (t >> 2);
        int col = nt * 16 + l16;
        float bv = b3[col];
#pragma unroll
        for (int r = 0; r < 4; r++) {
          int row0l = quad * 4 + r;
          float v0 = fmaxf(acc0[r] + bv, 0.0f);
          float v1 = fmaxf(acc1[r] + bv, 0.0f);
          int oct0 = (col >> 3) ^ (row0l & 7);
          h3s[row0l * 512 + oct0 * 8 + (col & 7)] = __half_as_ushort(__float2half(v0));
          int row1l = 16 + row0l;
          int oct1 = (col >> 3) ^ (row1l & 7);
          h3s[row1l * 512 + oct1 * 8 + (col & 7)] = __half_as_ushort(__float2half(v1));
        }
        acc0 = (f32x4){0, 0, 0, 0};
        acc1 = (f32x4){0, 0, 0, 0};
      }
    }
  }
  __syncthreads();

  // ---- phase 2: h3s @ Wi (K=512) + fold Wc; ring prefetch depth 3 ----
  float acc3[2][4][3] = {};
  {
    f32x4 acc0 = {0, 0, 0, 0}, acc1 = {0, 0, 0, 0};
    half8 bq[4];
#pragma unroll
    for (int p = 0; p < 3; p++)
      bq[p] = *(const half8*)&Wip[((ll64)(wave * 128 + p) * 64 + lane) * 8];
    int r0l = l16, r1l = 16 + l16;
    int sw0 = r0l & 7;
#pragma unroll 4
    for (int t = 0; t < 128; t++) {
      if (t + 3 < 128)
        bq[(t + 3) & 3] = *(const half8*)&Wip[((ll64)(wave * 128 + t + 3) * 64 + lane) * 8];
      half8 bcur = bq[t & 3];
      int kb = t & 15;
      int oct = ((kb * 4 + quad) ^ sw0);
      half8 a0 = *(const half8*)&h3s[r0l * 512 + oct * 8];
      half8 a1 = *(const half8*)&h3s[r1l * 512 + oct * 8];
      acc0 = __builtin_amdgcn_mfma_f32_16x16x32_f16(a0, bcur, acc0, 0, 0, 0);
      acc1 = __builtin_amdgcn_mfma_f32_16x16x32_f16(a1, bcur, acc1, 0, 0, 0);
      if (kb == 15) {
        int nt = wave * 8 + (t >> 4);
        int col = nt * 16 + l16;
        float bv = bi[col];
        float w0 = Wc[col * 3 + 0], w1 = Wc[col * 3 + 1], w2 = Wc[col * 3 + 2];
#pragma unroll
        for (int r = 0; r < 4; r++) {
          float v0 = fmaxf(acc0[r] + bv, 0.0f);
          float v1 = fmaxf(acc1[r] + bv, 0.0f);
          acc3[0][r][0] += v0 * w0; acc3[0][r][1] += v0 * w1; acc3[0][r][2] += v0 * w2;
          acc3[1][r][0] += v1 * w0; acc3[1][r][1] += v1 * w1; acc3[1][r][2] += v1 * w2;
        }
        acc0 = (f32x4){0, 0, 0, 0};
        acc1 = (f32x4){0, 0, 0, 0};
      }
    }
  }
#pragma unroll
  for (int rt = 0; rt < 2; rt++)
#pragma unroll
    for (int r = 0; r < 4; r++)
#pragma unroll
      for (int c = 0; c < 3; c++) {
        float v = acc3[rt][r][c];
        v += __shfl_xor(v, 1);
        v += __shfl_xor(v, 2);
        v += __shfl_xor(v, 4);
        v += __shfl_xor(v, 8);
        acc3[rt][r][c] = v;
      }
  if (l16 == 0) {
#pragma unroll
    for (int rt = 0; rt < 2; rt++)
#pragma unroll
      for (int r = 0; r < 4; r++)
#pragma unroll
        for (int c = 0; c < 3; c++)
          sRed[wave][rt * 16 + quad * 4 + r][c] = acc3[rt][r][c];
  }
  __syncthreads();
  if (tid < 96) {
    int row = tid / 3, c = tid % 3;
    out[(ll64)(row0 + row) * 3 + c] = sRed[0][row][c] + sRed[1][row][c] +
                                      sRed[2][row][c] + sRed[3][row][c] + bc[c];
  }
}

// ---------------- launcher ----------------
extern "C" void kernel_launch(void* const* d_in, const int* in_sizes, int n_in,
                              void* d_out, int out_size, void* d_ws, size_t ws_size,
                              hipStream_t stream) {
  const float* x  = (const float*)d_in[0];
  const void*  ei = d_in[1];
  const float* W1 = (const float*)d_in[2];
  const float* b1 = (const float*)d_in[3];
  const float* W2 = (const float*)d_in[4];
  const float* b2 = (const float*)d_in[5];
  const float* W3 = (const float*)d_in[6];
  const float* b3 = (const float*)d_in[7];
  const float* Wi = (const float*)d_in[8];
  const float* bi = (const float*)d_in[9];
  const float* Wc = (const float*)d_in[10];
  const float* bc = (const float*)d_in[11];
  float* out = (float*)d_out;

  char* ws = (char*)d_ws;
  const ll64 KB = 1ll << 10, MB = 1ll << 20;
  float* dinv  = (float*)(ws + 0);                 // 400 KB
  int*   offs  = (int*)(ws + 512 * KB);            // 400 KB (NN+1)
  int*   total = (int*)(ws + 1 * MB + 64 * KB);    // 1.6 KB
  int*   bbase = (int*)(ws + 1 * MB + 128 * KB);   // 1.6 KB
  int*   tbl   = (int*)(ws + 1 * MB + 192 * KB);   // 800 KB -> ends ~2 MB
  uint32* binned = (uint32*)(ws + 2 * MB);         // 12.8 MB -> 14.8
  int*   csr   = (int*)(ws + 15 * MB);             // 12.8 MB -> 27.8
  u16* pW1 = (u16*)(ws + 28 * MB);                 // 32 KB
  u16* pW2 = (u16*)(ws + 28 * MB + 64 * KB);       // 32 KB
  u16* pW3 = (u16*)(ws + 28 * MB + 128 * KB);      // 128 KB
  u16* pWi = (u16*)(ws + 28 * MB + 512 * KB);      // 512 KB
  u16* xh   = (u16*)(ws + 29 * MB);                // 25.6 MB -> 54.6
  u16* bufA = (u16*)(ws + 55 * MB);                // 25.6 MB -> 80.6
  u16* bufB = (u16*)(ws + 81 * MB);                // 25.6 MB -> 106.6

  const int TB = 256;
  k_binB<<<NBLK, TB, 0, stream>>>(ei, tbl);
  k_binC1<<<NB, NBLK, 0, stream>>>(tbl, total);
  k_binC2<<<1, 512, 0, stream>>>(total, bbase, offs);
  k_binD<<<NBLK, TB, 0, stream>>>(ei, tbl, bbase, binned);
  k_binE<<<NB, TB, 0, stream>>>(binned, bbase, total, offs, dinv, csr);
  // pack weights + convert x to dinv-prescaled fp16 (after binE: dinv ready)
  k_packhalf<<<(360448 + NN * 32 + TB - 1) / TB, TB, 0, stream>>>(
      W1, W2, W3, Wi, pW1, pW2, pW3, pWi, (const float4*)x, (ushort4*)xh, dinv);

  const int MBk = (NN + 63) / 64;  // 1563
  int aggBlocks = (NN + 15) / 16;  // 16 nodes per block (4 per wave)
  dim3 g128(MBk, 2);

  // layer 1
  k_agg<<<aggBlocks, TB, 0, stream>>>((const uint32*)xh, (uint32*)bufA, csr, offs, dinv, NN);
  k_gemm_mfma<<<g128, TB, 0, stream>>>(bufA, pW1, b1, dinv, bufB, NN, 128, 128);
  // layer 2
  k_agg<<<aggBlocks, TB, 0, stream>>>((const uint32*)bufB, (uint32*)bufA, csr, offs, dinv, NN);
  k_gemm_mfma<<<g128, TB, 0, stream>>>(bufA, pW2, b2, dinv, bufB, NN, 128, 128);
  // layer 3 aggregation, then fused GEMM512 + MLP head
  k_agg<<<aggBlocks, TB, 0, stream>>>((const uint32*)bufB, (uint32*)bufA, csr, offs, dinv, NN);
  k_tail32<<<NN / 32, TB, 0, stream>>>(bufA, pW3, b3, pWi, bi, Wc, bc, out, NN);
}

// Round 7
// 690.069 us; speedup vs baseline: 1.5346x; 1.0101x over previous
//
#include <hip/hip_runtime.h>
#include <hip/hip_fp16.h>

#define NN 100000
#define NE 3200000
#define NB 391          // coarse buckets of 256 nodes (dst >> 8)
#define NBLK 512        // edge-partition blocks for bin build
#define EPB 6250        // edges per block (NBLK * EPB == NE)
// dims: IN=128, HID=128, INT=512, OUT=3
// fp32 tensors on device; edge_index dtype probed per-block (int32/int64); fp32 out.
// Numerics: fp16 intermediates (dinv-prescaled) + single-pass fp16 weights; MFMA f16,
// fp32 acc (comparison floor measured at 1.2207e-4 = 2^-13).
// Round 13 (FAILED 129.5us): tail32 kb-outer, 8 live ntiles -> occ 2 blocks/CU.
// Round 14 (FAILED 149us): 2x4 ntile passes -> scratch spill. tail32 r12 form:
//   2 live acc tiles + occupancy 4; conflicts hidden by TLP.
// Round 15: agg 8-deep batches: NEUTRAL -> agg is L3-BW-bound, not latency-bound.
// Round 17 (FAILED 1059us): XCD-sliced chunk-major agg -> FETCH 256MB/dispatch;
//   slices not resident. REVERTED to row-major agg (~5% off L3-BW floor).
// Round 18: FUSE layer-3 agg INTO tail32 (k_tail32f). Gather (L3-BW, MFMA idle)
//   and tail32 phases (MFMA/LDS-bound, HBM 1.7%) are on disjoint resources ->
//   block-level pipelining overlaps them. Agg loop copied verbatim (bit-identical
//   accumulation order); result rounded to fp16 and staged in h3s scratch
//   (xor-swizzled octets), af fragments loaded, then phases 1/2 unchanged.
//   Eliminates bufA round-trip for layer 3.

typedef unsigned int uint32;
typedef unsigned short u16;
typedef long long ll64;
typedef __attribute__((ext_vector_type(8))) _Float16 half8;
typedef __attribute__((ext_vector_type(4))) float f32x4;

__device__ inline float2 h2f2(uint32 u) {
  __half2 h = *reinterpret_cast<__half2*>(&u);
  return __half22float2(h);
}
__device__ inline uint32 f2h2(float x, float y) {
  return (uint32)__half_as_ushort(__float2half(x)) |
         ((uint32)__half_as_ushort(__float2half(y)) << 16);
}
__device__ inline int edge_at(const void* ei, int is64, ll64 idx) {
  return is64 ? (int)((const ll64*)ei)[idx] : ((const int*)ei)[idx];
}
__device__ inline int detect64(const int* ei32) {
  int acc = 0;
#pragma unroll
  for (int k = 1; k < 32; k += 2) acc |= ei32[k];
  return (acc == 0) ? 1 : 0;
}

// ---- CSR build, 2-level counting sort ----
__global__ __launch_bounds__(256) void k_binB(const void* __restrict__ ei,
                                              int* __restrict__ tbl) {
  __shared__ int h[NB];
  __shared__ int sIs64;
  int k = blockIdx.x, tid = threadIdx.x;
  for (int i = tid; i < NB; i += 256) h[i] = 0;
  if (tid == 0) sIs64 = detect64((const int*)ei);
  __syncthreads();
  int is64 = sIs64;
  ll64 beg = (ll64)k * EPB, end = beg + EPB;
  for (ll64 i = beg + tid; i < end; i += 256)
    atomicAdd(&h[edge_at(ei, is64, (ll64)NE + i) >> 8], 1);
  __syncthreads();
  for (int i = tid; i < NB; i += 256) tbl[k * NB + i] = h[i];
}
__global__ __launch_bounds__(512) void k_binC1(int* __restrict__ tbl,
                                               int* __restrict__ total) {
  __shared__ int sd[NBLK];
  int b = blockIdx.x, tid = threadIdx.x;
  int v = tbl[tid * NB + b];
  sd[tid] = v;
  __syncthreads();
  for (int off = 1; off < NBLK; off <<= 1) {
    int t = (tid >= off) ? sd[tid - off] : 0;
    __syncthreads();
    sd[tid] += t;
    __syncthreads();
  }
  tbl[tid * NB + b] = sd[tid] - v;
  if (tid == NBLK - 1) total[b] = sd[NBLK - 1];
}
__global__ __launch_bounds__(512) void k_binC2(const int* __restrict__ total,
                                               int* __restrict__ bbase,
                                               int* __restrict__ offs) {
  __shared__ int sd[512];
  int tid = threadIdx.x;
  int v = (tid < NB) ? total[tid] : 0;
  sd[tid] = v;
  __syncthreads();
  for (int off = 1; off < 512; off <<= 1) {
    int t = (tid >= off) ? sd[tid - off] : 0;
    __syncthreads();
    sd[tid] += t;
    __syncthreads();
  }
  if (tid < NB) bbase[tid] = sd[tid] - v;
  if (tid == 0) offs[NN] = NE;
}
__global__ __launch_bounds__(256) void k_binD(const void* __restrict__ ei,
                                              const int* __restrict__ tbl,
                                              const int* __restrict__ bbase,
                                              uint32* __restrict__ binned) {
  __shared__ int lb[NB];
  __shared__ int lc[NB];
  __shared__ int sIs64;
  int k = blockIdx.x, tid = threadIdx.x;
  for (int i = tid; i < NB; i += 256) {
    lb[i] = tbl[k * NB + i] + bbase[i];
    lc[i] = 0;
  }
  if (tid == 0) sIs64 = detect64((const int*)ei);
  __syncthreads();
  int is64 = sIs64;
  ll64 beg = (ll64)k * EPB, end = beg + EPB;
  for (ll64 i = beg + tid; i < end; i += 256) {
    int s = edge_at(ei, is64, i);
    int d = edge_at(ei, is64, (ll64)NE + i);
    int b = d >> 8;
    int r = atomicAdd(&lc[b], 1);
    binned[lb[b] + r] = (uint32)s | ((uint32)(d & 255) << 24);
  }
}
__global__ __launch_bounds__(256) void k_binE(const uint32* __restrict__ binned,
                                              const int* __restrict__ bbase,
                                              const int* __restrict__ total,
                                              int* __restrict__ offs,
                                              float* __restrict__ dinv,
                                              int* __restrict__ csr) {
  __shared__ int cnt[256], pref[256], fil[256];
  int b = blockIdx.x, tid = threadIdx.x;
  cnt[tid] = 0;
  fil[tid] = 0;
  __syncthreads();
  int base = bbase[b], tot = total[b];
  for (int i = tid; i < tot; i += 256) atomicAdd(&cnt[binned[base + i] >> 24], 1);
  __syncthreads();
  int v = cnt[tid];
  pref[tid] = v;
  __syncthreads();
  for (int off = 1; off < 256; off <<= 1) {
    int t = (tid >= off) ? pref[tid - off] : 0;
    __syncthreads();
    pref[tid] += t;
    __syncthreads();
  }
  int myoff = pref[tid] - v;  // exclusive
  pref[tid] = myoff;
  int node = b * 256 + tid;
  if (node < NN) {
    offs[node] = base + myoff;
    dinv[node] = rsqrtf((float)(v + 1));  // +1: self-loop
  }
  __syncthreads();
  for (int i = tid; i < tot; i += 256) {
    uint32 w = binned[base + i];
    int dl = w >> 24;
    int r = atomicAdd(&fil[dl], 1);
    csr[base + pref[dl] + r] = (int)(w & 0xFFFFFFu);
  }
}

// ---- weight pack (fp16 B-fragment order) + x -> dinv-prescaled fp16 ----
__device__ inline void packOne(const float* __restrict__ W, u16* __restrict__ ph,
                               int K, int N, int t) {
  int j = t & 7, lane = (t >> 3) & 63, tl = t >> 9;
  int kbn = K >> 5;
  int kb = tl % kbn, ntile = tl / kbn;
  int k = kb * 32 + (lane >> 4) * 8 + j;
  int n2 = ntile * 16 + (lane & 15);
  ph[t] = __half_as_ushort(__float2half(W[k * N + n2]));
}
__global__ void k_packhalf(const float* W1, const float* W2, const float* W3,
                           const float* Wi, u16* p1, u16* p2, u16* p3, u16* pi,
                           const float4* __restrict__ x, ushort4* __restrict__ xh,
                           const float* __restrict__ dinv) {
  int t = blockIdx.x * blockDim.x + threadIdx.x;
  if (t < 16384) packOne(W1, p1, 128, 128, t);
  else if (t < 32768) packOne(W2, p2, 128, 128, t - 16384);
  else if (t < 98304) packOne(W3, p3, 128, 512, t - 32768);
  else if (t < 360448) packOne(Wi, pi, 512, 512, t - 98304);
  else {
    int i = t - 360448;
    if (i < NN * 32) {
      float4 v = x[i];
      float sc = dinv[i >> 5];  // 32 float4 per 128-dim row
      ushort4 o;
      o.x = __half_as_ushort(__float2half(v.x * sc));
      o.y = __half_as_ushort(__float2half(v.y * sc));
      o.z = __half_as_ushort(__float2half(v.z * sc));
      o.w = __half_as_ushort(__float2half(v.w * sc));
      xh[i] = o;
    }
  }
}

// ---- Aggregation: 4 nodes/wave (16 lanes per node, uint4 = 16B/lane gathers) ----
// input rows carry dinv[s]; out[i] = dinv[i]*(sum_s x'[s] + x'[i])
__global__ void k_agg(const uint32* __restrict__ xi, uint32* __restrict__ o,
                      const int* __restrict__ csr, const int* __restrict__ offs,
                      const float* __restrict__ dinv, int n) {
  int tid = threadIdx.x;
  int lane = tid & 63;
  int sub = lane >> 4, fl = lane & 15;
  int node = blockIdx.x * 16 + (tid >> 6) * 4 + sub;
  if (node >= n) return;
  int beg = offs[node], end = offs[node + 1];
  const uint4* xv = (const uint4*)xi;  // 16 uint4 per 128-dim row
  float acc[8] = {};
  int j = beg;
  for (; j + 7 < end; j += 8) {
    int s[8];
    uint4 r[8];
#pragma unroll
    for (int q = 0; q < 8; q++) s[q] = csr[j + q];
#pragma unroll
    for (int q = 0; q < 8; q++) r[q] = xv[(ll64)s[q] * 16 + fl];
#pragma unroll
    for (int q = 0; q < 8; q++) {
      float2 p0 = h2f2(r[q].x), p1 = h2f2(r[q].y);
      float2 p2 = h2f2(r[q].z), p3 = h2f2(r[q].w);
      acc[0] += p0.x; acc[1] += p0.y; acc[2] += p1.x; acc[3] += p1.y;
      acc[4] += p2.x; acc[5] += p2.y; acc[6] += p3.x; acc[7] += p3.y;
    }
  }
  for (; j + 3 < end; j += 4) {
    int s[4];
    uint4 r[4];
#pragma unroll
    for (int q = 0; q < 4; q++) s[q] = csr[j + q];
#pragma unroll
    for (int q = 0; q < 4; q++) r[q] = xv[(ll64)s[q] * 16 + fl];
#pragma unroll
    for (int q = 0; q < 4; q++) {
      float2 p0 = h2f2(r[q].x), p1 = h2f2(r[q].y);
      float2 p2 = h2f2(r[q].z), p3 = h2f2(r[q].w);
      acc[0] += p0.x; acc[1] += p0.y; acc[2] += p1.x; acc[3] += p1.y;
      acc[4] += p2.x; acc[5] += p2.y; acc[6] += p3.x; acc[7] += p3.y;
    }
  }
  for (; j < end; j++) {
    uint4 r = xv[(ll64)csr[j] * 16 + fl];
    float2 p0 = h2f2(r.x), p1 = h2f2(r.y), p2 = h2f2(r.z), p3 = h2f2(r.w);
    acc[0] += p0.x; acc[1] += p0.y; acc[2] += p1.x; acc[3] += p1.y;
    acc[4] += p2.x; acc[5] += p2.y; acc[6] += p3.x; acc[7] += p3.y;
  }
  float di = dinv[node];
  uint4 sf = xv[(ll64)node * 16 + fl];
  float2 q0 = h2f2(sf.x), q1 = h2f2(sf.y), q2 = h2f2(sf.z), q3 = h2f2(sf.w);
  uint4 ov;
  ov.x = f2h2(di * (acc[0] + q0.x), di * (acc[1] + q0.y));
  ov.y = f2h2(di * (acc[2] + q1.x), di * (acc[3] + q1.y));
  ov.z = f2h2(di * (acc[4] + q2.x), di * (acc[5] + q2.y));
  ov.w = f2h2(di * (acc[6] + q3.x), di * (acc[7] + q3.y));
  ((uint4*)o)[(ll64)node * 16 + fl] = ov;
}

// -- MFMA GEMM: C = dinv[row]*relu(A@W + bias) (pre-scaled for next agg); reg dbuf --
__global__ __launch_bounds__(256, 4) void k_gemm_mfma(
    const u16* __restrict__ A, const u16* __restrict__ Bp,
    const float* __restrict__ bias, const float* __restrict__ dscale,
    u16* __restrict__ Co, int M, int N, int K) {
  int wave = threadIdx.x >> 6, lane = threadIdx.x & 63;
  int quad = lane >> 4, l16 = lane & 15;
  int row0 = blockIdx.x * 64, col0 = blockIdx.y * 64;
  int m = row0 + wave * 16 + l16;
  int mc = (m < M) ? m : (M - 1);
  int kbn = K >> 5;
  f32x4 acc[4] = {{0,0,0,0},{0,0,0,0},{0,0,0,0},{0,0,0,0}};
  const half8* Ar = (const half8*)&A[(ll64)mc * K];
  half8 ac = Ar[quad];
  half8 an = ac;
  half8 bc_[4], bn_[4];
#pragma unroll
  for (int nt = 0; nt < 4; nt++)
    bc_[nt] = *(const half8*)&Bp[((ll64)(((col0 >> 4) + nt) * kbn) * 64 + lane) * 8];
  for (int kb = 0; kb < kbn; kb++) {
    int kn = kb + 1;
    if (kn < kbn) {
      an = Ar[kn * 4 + quad];
#pragma unroll
      for (int nt = 0; nt < 4; nt++)
        bn_[nt] = *(const half8*)&Bp[((ll64)(((col0 >> 4) + nt) * kbn + kn) * 64 + lane) * 8];
    }
#pragma unroll
    for (int nt = 0; nt < 4; nt++)
      acc[nt] = __builtin_amdgcn_mfma_f32_16x16x32_f16(ac, bc_[nt], acc[nt], 0, 0, 0);
    ac = an;
#pragma unroll
    for (int nt = 0; nt < 4; nt++) bc_[nt] = bn_[nt];
  }
  float ds[4];
#pragma unroll
  for (int r = 0; r < 4; r++) {
    int rr = row0 + wave * 16 + quad * 4 + r;
    ds[r] = dscale[(rr < M) ? rr : (M - 1)];
  }
#pragma unroll
  for (int nt = 0; nt < 4; nt++) {
    int cc = col0 + nt * 16 + l16;
    float bv = bias[cc];
#pragma unroll
    for (int r = 0; r < 4; r++) {
      int rr = row0 + wave * 16 + quad * 4 + r;
      if (rr < M)
        Co[(ll64)rr * N + cc] =
            __half_as_ushort(__float2half(fmaxf(acc[nt][r] + bv, 0.0f) * ds[r]));
    }
  }
}

// ---- Fused layer-3 agg + tail 32-row: gather 32 nodes -> fp16 tile in h3s
// scratch (octet xor-swizzle) -> af frags -> phase1 (h3 = a3@W3, LDS) ->
// phase2 (h3@Wi + fold Wc). Phases identical to r12 tail32; agg loop identical
// to k_agg (bit-identical numerics). Gather (L3-BW) overlaps other blocks'
// MFMA/LDS phases via 4 blocks/CU.
__global__ __launch_bounds__(256, 4) void k_tail32f(
    const u16* __restrict__ xin, const int* __restrict__ csr,
    const int* __restrict__ offs, const float* __restrict__ dinv,
    const u16* __restrict__ W3p, const float* __restrict__ b3,
    const u16* __restrict__ Wip, const float* __restrict__ bi,
    const float* __restrict__ Wc, const float* __restrict__ bc,
    float* __restrict__ out, int M) {
  __shared__ u16 h3s[32 * 512];     // 32 KB; first 8 KB doubles as agg tile
  __shared__ float sRed[4][32][3];  // 1.5 KB
  int tid = threadIdx.x;
  int wave = tid >> 6, lane = tid & 63, quad = lane >> 4, l16 = lane & 15;
  int row0 = blockIdx.x * 32;  // NN % 32 == 0

  // ---- phase 0: aggregate 32 nodes (2 rounds x 4 nodes/wave) ----
  {
    int sub = lane >> 4, fl = lane & 15;
    const uint4* xv = (const uint4*)xin;
#pragma unroll
    for (int rnd = 0; rnd < 2; rnd++) {
      int nloc = rnd * 16 + wave * 4 + sub;
      int node = row0 + nloc;
      int beg = offs[node], end = offs[node + 1];
      float acc[8] = {};
      int j = beg;
      for (; j + 7 < end; j += 8) {
        int s[8];
        uint4 r[8];
#pragma unroll
        for (int q = 0; q < 8; q++) s[q] = csr[j + q];
#pragma unroll
        for (int q = 0; q < 8; q++) r[q] = xv[(ll64)s[q] * 16 + fl];
#pragma unroll
        for (int q = 0; q < 8; q++) {
          float2 p0 = h2f2(r[q].x), p1 = h2f2(r[q].y);
          float2 p2 = h2f2(r[q].z), p3 = h2f2(r[q].w);
          acc[0] += p0.x; acc[1] += p0.y; acc[2] += p1.x; acc[3] += p1.y;
          acc[4] += p2.x; acc[5] += p2.y; acc[6] += p3.x; acc[7] += p3.y;
        }
      }
      for (; j + 3 < end; j += 4) {
        int s[4];
        uint4 r[4];
#pragma unroll
        for (int q = 0; q < 4; q++) s[q] = csr[j + q];
#pragma unroll
        for (int q = 0; q < 4; q++) r[q] = xv[(ll64)s[q] * 16 + fl];
#pragma unroll
        for (int q = 0; q < 4; q++) {
          float2 p0 = h2f2(r[q].x), p1 = h2f2(r[q].y);
          float2 p2 = h2f2(r[q].z), p3 = h2f2(r[q].w);
          acc[0] += p0.x; acc[1] += p0.y; acc[2] += p1.x; acc[3] += p1.y;
          acc[4] += p2.x; acc[5] += p2.y; acc[6] += p3.x; acc[7] += p3.y;
        }
      }
      for (; j < end; j++) {
        uint4 r = xv[(ll64)csr[j] * 16 + fl];
        float2 p0 = h2f2(r.x), p1 = h2f2(r.y), p2 = h2f2(r.z), p3 = h2f2(r.w);
        acc[0] += p0.x; acc[1] += p0.y; acc[2] += p1.x; acc[3] += p1.y;
        acc[4] += p2.x; acc[5] += p2.y; acc[6] += p3.x; acc[7] += p3.y;
      }
      float di = dinv[node];
      uint4 sf = xv[(ll64)node * 16 + fl];
      float2 q0 = h2f2(sf.x), q1 = h2f2(sf.y), q2 = h2f2(sf.z), q3 = h2f2(sf.w);
      uint4 ov;
      ov.x = f2h2(di * (acc[0] + q0.x), di * (acc[1] + q0.y));
      ov.y = f2h2(di * (acc[2] + q1.x), di * (acc[3] + q1.y));
      ov.z = f2h2(di * (acc[4] + q2.x), di * (acc[5] + q2.y));
      ov.w = f2h2(di * (acc[6] + q3.x), di * (acc[7] + q3.y));
      // stage into h3s scratch: row nloc, dims-octet fl at pos fl^(nloc&7)
      *(uint4*)&h3s[nloc * 128 + ((fl ^ (nloc & 7)) << 3)] = ov;
    }
  }
  __syncthreads();
  half8 af[2][4];
#pragma unroll
  for (int rt = 0; rt < 2; rt++) {
    int row = rt * 16 + l16;
#pragma unroll
    for (int kb = 0; kb < 4; kb++)
      af[rt][kb] = *(const half8*)&h3s[row * 128 + (((kb * 4 + quad) ^ (row & 7)) << 3)];
  }
  __syncthreads();  // all af reads done before phase 1 overwrites h3s

  // ---- phase 1: 32x512 = a3[32x128] @ W3 into LDS; ring prefetch depth 3 ----
  {
    f32x4 acc0 = {0, 0, 0, 0}, acc1 = {0, 0, 0, 0};
    half8 bq[4];
#pragma unroll
    for (int p = 0; p < 3; p++)
      bq[p] = *(const half8*)&W3p[((ll64)(wave * 32 + p) * 64 + lane) * 8];
#pragma unroll 4
    for (int t = 0; t < 32; t++) {
      if (t + 3 < 32)
        bq[(t + 3) & 3] = *(const half8*)&W3p[((ll64)(wave * 32 + t + 3) * 64 + lane) * 8];
      half8 bcur = bq[t & 3];
      int kb = t & 3;
      acc0 = __builtin_amdgcn_mfma_f32_16x16x32_f16(af[0][kb], bcur, acc0, 0, 0, 0);
      acc1 = __builtin_amdgcn_mfma_f32_16x16x32_f16(af[1][kb], bcur, acc1, 0, 0, 0);
      if (kb == 3) {
        int nt = wave * 8 + (t >> 2);
        int col = nt * 16 + l16;
        float bv = b3[col];
#pragma unroll
        for (int r = 0; r < 4; r++) {
          int row0l = quad * 4 + r;
          float v0 = fmaxf(acc0[r] + bv, 0.0f);
          float v1 = fmaxf(acc1[r] + bv, 0.0f);
          int oct0 = (col >> 3) ^ (row0l & 7);
          h3s[row0l * 512 + oct0 * 8 + (col & 7)] = __half_as_ushort(__float2half(v0));
          int row1l = 16 + row0l;
          int oct1 = (col >> 3) ^ (row1l & 7);
          h3s[row1l * 512 + oct1 * 8 + (col & 7)] = __half_as_ushort(__float2half(v1));
        }
        acc0 = (f32x4){0, 0, 0, 0};
        acc1 = (f32x4){0, 0, 0, 0};
      }
    }
  }
  __syncthreads();

  // ---- phase 2: h3s @ Wi (K=512) + fold Wc; ring prefetch depth 3 ----
  float acc3[2][4][3] = {};
  {
    f32x4 acc0 = {0, 0, 0, 0}, acc1 = {0, 0, 0, 0};
    half8 bq[4];
#pragma unroll
    for (int p = 0; p < 3; p++)
      bq[p] = *(const half8*)&Wip[((ll64)(wave * 128 + p) * 64 + lane) * 8];
    int r0l = l16, r1l = 16 + l16;
    int sw0 = r0l & 7;
#pragma unroll 4
    for (int t = 0; t < 128; t++) {
      if (t + 3 < 128)
        bq[(t + 3) & 3] = *(const half8*)&Wip[((ll64)(wave * 128 + t + 3) * 64 + lane) * 8];
      half8 bcur = bq[t & 3];
      int kb = t & 15;
      int oct = ((kb * 4 + quad) ^ sw0);
      half8 a0 = *(const half8*)&h3s[r0l * 512 + oct * 8];
      half8 a1 = *(const half8*)&h3s[r1l * 512 + oct * 8];
      acc0 = __builtin_amdgcn_mfma_f32_16x16x32_f16(a0, bcur, acc0, 0, 0, 0);
      acc1 = __builtin_amdgcn_mfma_f32_16x16x32_f16(a1, bcur, acc1, 0, 0, 0);
      if (kb == 15) {
        int nt = wave * 8 + (t >> 4);
        int col = nt * 16 + l16;
        float bv = bi[col];
        float w0 = Wc[col * 3 + 0], w1 = Wc[col * 3 + 1], w2 = Wc[col * 3 + 2];
#pragma unroll
        for (int r = 0; r < 4; r++) {
          float v0 = fmaxf(acc0[r] + bv, 0.0f);
          float v1 = fmaxf(acc1[r] + bv, 0.0f);
          acc3[0][r][0] += v0 * w0; acc3[0][r][1] += v0 * w1; acc3[0][r][2] += v0 * w2;
          acc3[1][r][0] += v1 * w0; acc3[1][r][1] += v1 * w1; acc3[1][r][2] += v1 * w2;
        }
        acc0 = (f32x4){0, 0, 0, 0};
        acc1 = (f32x4){0, 0, 0, 0};
      }
    }
  }
#pragma unroll
  for (int rt = 0; rt < 2; rt++)
#pragma unroll
    for (int r = 0; r < 4; r++)
#pragma unroll
      for (int c = 0; c < 3; c++) {
        float v = acc3[rt][r][c];
        v += __shfl_xor(v, 1);
        v += __shfl_xor(v, 2);
        v += __shfl_xor(v, 4);
        v += __shfl_xor(v, 8);
        acc3[rt][r][c] = v;
      }
  if (l16 == 0) {
#pragma unroll
    for (int rt = 0; rt < 2; rt++)
#pragma unroll
      for (int r = 0; r < 4; r++)
#pragma unroll
        for (int c = 0; c < 3; c++)
          sRed[wave][rt * 16 + quad * 4 + r][c] = acc3[rt][r][c];
  }
  __syncthreads();
  if (tid < 96) {
    int row = tid / 3, c = tid % 3;
    out[(ll64)(row0 + row) * 3 + c] = sRed[0][row][c] + sRed[1][row][c] +
                                      sRed[2][row][c] + sRed[3][row][c] + bc[c];
  }
}

// ---------------- launcher ----------------
extern "C" void kernel_launch(void* const* d_in, const int* in_sizes, int n_in,
                              void* d_out, int out_size, void* d_ws, size_t ws_size,
                              hipStream_t stream) {
  const float* x  = (const float*)d_in[0];
  const void*  ei = d_in[1];
  const float* W1 = (const float*)d_in[2];
  const float* b1 = (const float*)d_in[3];
  const float* W2 = (const float*)d_in[4];
  const float* b2 = (const float*)d_in[5];
  const float* W3 = (const float*)d_in[6];
  const float* b3 = (const float*)d_in[7];
  const float* Wi = (const float*)d_in[8];
  const float* bi = (const float*)d_in[9];
  const float* Wc = (const float*)d_in[10];
  const float* bc = (const float*)d_in[11];
  float* out = (float*)d_out;

  char* ws = (char*)d_ws;
  const ll64 KB = 1ll << 10, MB = 1ll << 20;
  float* dinv  = (float*)(ws + 0);                 // 400 KB
  int*   offs  = (int*)(ws + 512 * KB);            // 400 KB (NN+1)
  int*   total = (int*)(ws + 1 * MB + 64 * KB);    // 1.6 KB
  int*   bbase = (int*)(ws + 1 * MB + 128 * KB);   // 1.6 KB
  int*   tbl   = (int*)(ws + 1 * MB + 192 * KB);   // 800 KB -> ends ~2 MB
  uint32* binned = (uint32*)(ws + 2 * MB);         // 12.8 MB -> 14.8
  int*   csr   = (int*)(ws + 15 * MB);             // 12.8 MB -> 27.8
  u16* pW1 = (u16*)(ws + 28 * MB);                 // 32 KB
  u16* pW2 = (u16*)(ws + 28 * MB + 64 * KB);       // 32 KB
  u16* pW3 = (u16*)(ws + 28 * MB + 128 * KB);      // 128 KB
  u16* pWi = (u16*)(ws + 28 * MB + 512 * KB);      // 512 KB
  u16* xh   = (u16*)(ws + 29 * MB);                // 25.6 MB -> 54.6
  u16* bufA = (u16*)(ws + 55 * MB);                // 25.6 MB -> 80.6
  u16* bufB = (u16*)(ws + 81 * MB);                // 25.6 MB -> 106.6

  const int TB = 256;
  k_binB<<<NBLK, TB, 0, stream>>>(ei, tbl);
  k_binC1<<<NB, NBLK, 0, stream>>>(tbl, total);
  k_binC2<<<1, 512, 0, stream>>>(total, bbase, offs);
  k_binD<<<NBLK, TB, 0, stream>>>(ei, tbl, bbase, binned);
  k_binE<<<NB, TB, 0, stream>>>(binned, bbase, total, offs, dinv, csr);
  // pack weights + convert x to dinv-prescaled fp16 (after binE: dinv ready)
  k_packhalf<<<(360448 + NN * 32 + TB - 1) / TB, TB, 0, stream>>>(
      W1, W2, W3, Wi, pW1, pW2, pW3, pWi, (const float4*)x, (ushort4*)xh, dinv);

  const int MBk = (NN + 63) / 64;  // 1563
  int aggBlocks = (NN + 15) / 16;  // 16 nodes per block (4 per wave)
  dim3 g128(MBk, 2);

  // layer 1
  k_agg<<<aggBlocks, TB, 0, stream>>>((const uint32*)xh, (uint32*)bufA, csr, offs, dinv, NN);
  k_gemm_mfma<<<g128, TB, 0, stream>>>(bufA, pW1, b1, dinv, bufB, NN, 128, 128);
  // layer 2
  k_agg<<<aggBlocks, TB, 0, stream>>>((const uint32*)bufB, (uint32*)bufA, csr, offs, dinv, NN);
  k_gemm_mfma<<<g128, TB, 0, stream>>>(bufA, pW2, b2, dinv, bufB, NN, 128, 128);
  // layer 3: fused aggregation + GEMM512 + MLP head (reads bufB directly)
  k_tail32f<<<NN / 32, TB, 0, stream>>>(bufB, csr, offs, dinv, pW3, b3, pWi, bi,
                                        Wc, bc, out, NN);
}

// Round 8
// 689.360 us; speedup vs baseline: 1.5362x; 1.0010x over previous
//
#include <hip/hip_runtime.h>
#include <hip/hip_fp16.h>

#define NN 100000
#define NE 3200000
#define NB 391          // coarse buckets of 256 nodes (dst >> 8)
#define NBLK 512        // edge-partition blocks for bin build
#define EPB 6250        // edges per block (NBLK * EPB == NE)
// dims: IN=128, HID=128, INT=512, OUT=3
// fp32 tensors on device; edge_index dtype probed per-block (int32/int64); fp32 out.
// Numerics: fp16 intermediates (dinv-prescaled) + single-pass fp16 weights; MFMA f16,
// fp32 acc (comparison floor measured at 1.2207e-4 = 2^-13).
// r13 (FAILED): tail32 kb-outer 8 ntiles -> occ 2. r14 (FAILED): spill.
// r15: agg depth-8 NEUTRAL -> L3-BW-bound. r17 (FAILED): XCD-slice -> FETCH 256MB.
// r18 (690us): fused layer-3 agg into tail32 (k_tail32f); FETCH 370MB shows
//   gather L2-miss traffic dominates; VGPR stayed 52, no spill.
// r19: same fusion for layers 1+2 (k_fusedL = phase0 gather + 8-MFMA epilogue,
//   K=128). Deletes 2 launches + 2x 51.2MB bufA round-trips. Bit-identical
//   numerics (same CSR accumulation order, same kb order as k_gemm_mfma).

typedef unsigned int uint32;
typedef unsigned short u16;
typedef long long ll64;
typedef __attribute__((ext_vector_type(8))) _Float16 half8;
typedef __attribute__((ext_vector_type(4))) float f32x4;

__device__ inline float2 h2f2(uint32 u) {
  __half2 h = *reinterpret_cast<__half2*>(&u);
  return __half22float2(h);
}
__device__ inline uint32 f2h2(float x, float y) {
  return (uint32)__half_as_ushort(__float2half(x)) |
         ((uint32)__half_as_ushort(__float2half(y)) << 16);
}
__device__ inline int edge_at(const void* ei, int is64, ll64 idx) {
  return is64 ? (int)((const ll64*)ei)[idx] : ((const int*)ei)[idx];
}
__device__ inline int detect64(const int* ei32) {
  int acc = 0;
#pragma unroll
  for (int k = 1; k < 32; k += 2) acc |= ei32[k];
  return (acc == 0) ? 1 : 0;
}

// ---- CSR build, 2-level counting sort ----
__global__ __launch_bounds__(256) void k_binB(const void* __restrict__ ei,
                                              int* __restrict__ tbl) {
  __shared__ int h[NB];
  __shared__ int sIs64;
  int k = blockIdx.x, tid = threadIdx.x;
  for (int i = tid; i < NB; i += 256) h[i] = 0;
  if (tid == 0) sIs64 = detect64((const int*)ei);
  __syncthreads();
  int is64 = sIs64;
  ll64 beg = (ll64)k * EPB, end = beg + EPB;
  for (ll64 i = beg + tid; i < end; i += 256)
    atomicAdd(&h[edge_at(ei, is64, (ll64)NE + i) >> 8], 1);
  __syncthreads();
  for (int i = tid; i < NB; i += 256) tbl[k * NB + i] = h[i];
}
__global__ __launch_bounds__(512) void k_binC1(int* __restrict__ tbl,
                                               int* __restrict__ total) {
  __shared__ int sd[NBLK];
  int b = blockIdx.x, tid = threadIdx.x;
  int v = tbl[tid * NB + b];
  sd[tid] = v;
  __syncthreads();
  for (int off = 1; off < NBLK; off <<= 1) {
    int t = (tid >= off) ? sd[tid - off] : 0;
    __syncthreads();
    sd[tid] += t;
    __syncthreads();
  }
  tbl[tid * NB + b] = sd[tid] - v;
  if (tid == NBLK - 1) total[b] = sd[NBLK - 1];
}
__global__ __launch_bounds__(512) void k_binC2(const int* __restrict__ total,
                                               int* __restrict__ bbase,
                                               int* __restrict__ offs) {
  __shared__ int sd[512];
  int tid = threadIdx.x;
  int v = (tid < NB) ? total[tid] : 0;
  sd[tid] = v;
  __syncthreads();
  for (int off = 1; off < 512; off <<= 1) {
    int t = (tid >= off) ? sd[tid - off] : 0;
    __syncthreads();
    sd[tid] += t;
    __syncthreads();
  }
  if (tid < NB) bbase[tid] = sd[tid] - v;
  if (tid == 0) offs[NN] = NE;
}
__global__ __launch_bounds__(256) void k_binD(const void* __restrict__ ei,
                                              const int* __restrict__ tbl,
                                              const int* __restrict__ bbase,
                                              uint32* __restrict__ binned) {
  __shared__ int lb[NB];
  __shared__ int lc[NB];
  __shared__ int sIs64;
  int k = blockIdx.x, tid = threadIdx.x;
  for (int i = tid; i < NB; i += 256) {
    lb[i] = tbl[k * NB + i] + bbase[i];
    lc[i] = 0;
  }
  if (tid == 0) sIs64 = detect64((const int*)ei);
  __syncthreads();
  int is64 = sIs64;
  ll64 beg = (ll64)k * EPB, end = beg + EPB;
  for (ll64 i = beg + tid; i < end; i += 256) {
    int s = edge_at(ei, is64, i);
    int d = edge_at(ei, is64, (ll64)NE + i);
    int b = d >> 8;
    int r = atomicAdd(&lc[b], 1);
    binned[lb[b] + r] = (uint32)s | ((uint32)(d & 255) << 24);
  }
}
__global__ __launch_bounds__(256) void k_binE(const uint32* __restrict__ binned,
                                              const int* __restrict__ bbase,
                                              const int* __restrict__ total,
                                              int* __restrict__ offs,
                                              float* __restrict__ dinv,
                                              int* __restrict__ csr) {
  __shared__ int cnt[256], pref[256], fil[256];
  int b = blockIdx.x, tid = threadIdx.x;
  cnt[tid] = 0;
  fil[tid] = 0;
  __syncthreads();
  int base = bbase[b], tot = total[b];
  for (int i = tid; i < tot; i += 256) atomicAdd(&cnt[binned[base + i] >> 24], 1);
  __syncthreads();
  int v = cnt[tid];
  pref[tid] = v;
  __syncthreads();
  for (int off = 1; off < 256; off <<= 1) {
    int t = (tid >= off) ? pref[tid - off] : 0;
    __syncthreads();
    pref[tid] += t;
    __syncthreads();
  }
  int myoff = pref[tid] - v;  // exclusive
  pref[tid] = myoff;
  int node = b * 256 + tid;
  if (node < NN) {
    offs[node] = base + myoff;
    dinv[node] = rsqrtf((float)(v + 1));  // +1: self-loop
  }
  __syncthreads();
  for (int i = tid; i < tot; i += 256) {
    uint32 w = binned[base + i];
    int dl = w >> 24;
    int r = atomicAdd(&fil[dl], 1);
    csr[base + pref[dl] + r] = (int)(w & 0xFFFFFFu);
  }
}

// ---- weight pack (fp16 B-fragment order) + x -> dinv-prescaled fp16 ----
__device__ inline void packOne(const float* __restrict__ W, u16* __restrict__ ph,
                               int K, int N, int t) {
  int j = t & 7, lane = (t >> 3) & 63, tl = t >> 9;
  int kbn = K >> 5;
  int kb = tl % kbn, ntile = tl / kbn;
  int k = kb * 32 + (lane >> 4) * 8 + j;
  int n2 = ntile * 16 + (lane & 15);
  ph[t] = __half_as_ushort(__float2half(W[k * N + n2]));
}
__global__ void k_packhalf(const float* W1, const float* W2, const float* W3,
                           const float* Wi, u16* p1, u16* p2, u16* p3, u16* pi,
                           const float4* __restrict__ x, ushort4* __restrict__ xh,
                           const float* __restrict__ dinv) {
  int t = blockIdx.x * blockDim.x + threadIdx.x;
  if (t < 16384) packOne(W1, p1, 128, 128, t);
  else if (t < 32768) packOne(W2, p2, 128, 128, t - 16384);
  else if (t < 98304) packOne(W3, p3, 128, 512, t - 32768);
  else if (t < 360448) packOne(Wi, pi, 512, 512, t - 98304);
  else {
    int i = t - 360448;
    if (i < NN * 32) {
      float4 v = x[i];
      float sc = dinv[i >> 5];  // 32 float4 per 128-dim row
      ushort4 o;
      o.x = __half_as_ushort(__float2half(v.x * sc));
      o.y = __half_as_ushort(__float2half(v.y * sc));
      o.z = __half_as_ushort(__float2half(v.z * sc));
      o.w = __half_as_ushort(__float2half(v.w * sc));
      xh[i] = o;
    }
  }
}

// ---- phase 0 helper: aggregate 32 nodes into LDS tile (octet xor-swizzled) ----
// Identical accumulation order to the original k_agg -> bit-identical numerics.
__device__ inline void agg32_phase0(const u16* __restrict__ xin,
                                    const int* __restrict__ csr,
                                    const int* __restrict__ offs,
                                    const float* __restrict__ dinv,
                                    int row0, int tid, u16* __restrict__ tile) {
  int lane = tid & 63, wave = tid >> 6;
  int sub = lane >> 4, fl = lane & 15;
  const uint4* xv = (const uint4*)xin;
#pragma unroll
  for (int rnd = 0; rnd < 2; rnd++) {
    int nloc = rnd * 16 + wave * 4 + sub;
    int node = row0 + nloc;
    int beg = offs[node], end = offs[node + 1];
    float acc[8] = {};
    int j = beg;
    for (; j + 7 < end; j += 8) {
      int s[8];
      uint4 r[8];
#pragma unroll
      for (int q = 0; q < 8; q++) s[q] = csr[j + q];
#pragma unroll
      for (int q = 0; q < 8; q++) r[q] = xv[(ll64)s[q] * 16 + fl];
#pragma unroll
      for (int q = 0; q < 8; q++) {
        float2 p0 = h2f2(r[q].x), p1 = h2f2(r[q].y);
        float2 p2 = h2f2(r[q].z), p3 = h2f2(r[q].w);
        acc[0] += p0.x; acc[1] += p0.y; acc[2] += p1.x; acc[3] += p1.y;
        acc[4] += p2.x; acc[5] += p2.y; acc[6] += p3.x; acc[7] += p3.y;
      }
    }
    for (; j + 3 < end; j += 4) {
      int s[4];
      uint4 r[4];
#pragma unroll
      for (int q = 0; q < 4; q++) s[q] = csr[j + q];
#pragma unroll
      for (int q = 0; q < 4; q++) r[q] = xv[(ll64)s[q] * 16 + fl];
#pragma unroll
      for (int q = 0; q < 4; q++) {
        float2 p0 = h2f2(r[q].x), p1 = h2f2(r[q].y);
        float2 p2 = h2f2(r[q].z), p3 = h2f2(r[q].w);
        acc[0] += p0.x; acc[1] += p0.y; acc[2] += p1.x; acc[3] += p1.y;
        acc[4] += p2.x; acc[5] += p2.y; acc[6] += p3.x; acc[7] += p3.y;
      }
    }
    for (; j < end; j++) {
      uint4 r = xv[(ll64)csr[j] * 16 + fl];
      float2 p0 = h2f2(r.x), p1 = h2f2(r.y), p2 = h2f2(r.z), p3 = h2f2(r.w);
      acc[0] += p0.x; acc[1] += p0.y; acc[2] += p1.x; acc[3] += p1.y;
      acc[4] += p2.x; acc[5] += p2.y; acc[6] += p3.x; acc[7] += p3.y;
    }
    float di = dinv[node];
    uint4 sf = xv[(ll64)node * 16 + fl];
    float2 q0 = h2f2(sf.x), q1 = h2f2(sf.y), q2 = h2f2(sf.z), q3 = h2f2(sf.w);
    uint4 ov;
    ov.x = f2h2(di * (acc[0] + q0.x), di * (acc[1] + q0.y));
    ov.y = f2h2(di * (acc[2] + q1.x), di * (acc[3] + q1.y));
    ov.z = f2h2(di * (acc[4] + q2.x), di * (acc[5] + q2.y));
    ov.w = f2h2(di * (acc[6] + q3.x), di * (acc[7] + q3.y));
    *(uint4*)&tile[nloc * 128 + ((fl ^ (nloc & 7)) << 3)] = ov;
  }
}

// ---- af loader: MFMA A-fragments for 2 row-tiles from the swizzled tile ----
__device__ inline void load_af(const u16* __restrict__ tile, int lane,
                               half8 af[2][4]) {
  int quad = (lane >> 4), l16 = lane & 15;
#pragma unroll
  for (int rt = 0; rt < 2; rt++) {
    int row = rt * 16 + l16;
#pragma unroll
    for (int kb = 0; kb < 4; kb++)
      af[rt][kb] = *(const half8*)&tile[row * 128 + (((kb * 4 + quad) ^ (row & 7)) << 3)];
  }
}

// ---- Fused layer (1/2): gather 32 nodes + GEMM128 epilogue ----
// Co[row] = dinv[row]*relu(agg_row @ W + bias), fp16; same kb order as old gemm.
__global__ __launch_bounds__(256, 4) void k_fusedL(
    const u16* __restrict__ xin, const int* __restrict__ csr,
    const int* __restrict__ offs, const float* __restrict__ dinv,
    const u16* __restrict__ Wp, const float* __restrict__ bias,
    u16* __restrict__ Co) {
  __shared__ u16 tile[32 * 128];  // 8 KB
  int tid = threadIdx.x;
  int wave = tid >> 6, lane = tid & 63, quad = lane >> 4, l16 = lane & 15;
  int row0 = blockIdx.x * 32;  // NN % 32 == 0
  agg32_phase0(xin, csr, offs, dinv, row0, tid, tile);
  __syncthreads();
  half8 af[2][4];
  load_af(tile, lane, af);
#pragma unroll
  for (int p = 0; p < 2; p++) {
    int nt = wave * 2 + p;  // col-tile 0..7 (N=128)
    half8 bv[4];
#pragma unroll
    for (int kb = 0; kb < 4; kb++)
      bv[kb] = *(const half8*)&Wp[((ll64)(nt * 4 + kb) * 64 + lane) * 8];
    f32x4 acc0 = {0, 0, 0, 0}, acc1 = {0, 0, 0, 0};
#pragma unroll
    for (int kb = 0; kb < 4; kb++) {
      acc0 = __builtin_amdgcn_mfma_f32_16x16x32_f16(af[0][kb], bv[kb], acc0, 0, 0, 0);
      acc1 = __builtin_amdgcn_mfma_f32_16x16x32_f16(af[1][kb], bv[kb], acc1, 0, 0, 0);
    }
    int col = nt * 16 + l16;
    float bvv = bias[col];
#pragma unroll
    for (int r = 0; r < 4; r++) {
      int r0 = quad * 4 + r, r1 = r0 + 16;
      Co[(ll64)(row0 + r0) * 128 + col] =
          __half_as_ushort(__float2half(fmaxf(acc0[r] + bvv, 0.0f) * dinv[row0 + r0]));
      Co[(ll64)(row0 + r1) * 128 + col] =
          __half_as_ushort(__float2half(fmaxf(acc1[r] + bvv, 0.0f) * dinv[row0 + r1]));
    }
  }
}

// ---- Fused layer-3 agg + tail 32-row (r18 form, phase0 via helper) ----
__global__ __launch_bounds__(256, 4) void k_tail32f(
    const u16* __restrict__ xin, const int* __restrict__ csr,
    const int* __restrict__ offs, const float* __restrict__ dinv,
    const u16* __restrict__ W3p, const float* __restrict__ b3,
    const u16* __restrict__ Wip, const float* __restrict__ bi,
    const float* __restrict__ Wc, const float* __restrict__ bc,
    float* __restrict__ out, int M) {
  __shared__ u16 h3s[32 * 512];     // 32 KB; first 8 KB doubles as agg tile
  __shared__ float sRed[4][32][3];  // 1.5 KB
  int tid = threadIdx.x;
  int wave = tid >> 6, lane = tid & 63, quad = lane >> 4, l16 = lane & 15;
  int row0 = blockIdx.x * 32;  // NN % 32 == 0

  agg32_phase0(xin, csr, offs, dinv, row0, tid, h3s);
  __syncthreads();
  half8 af[2][4];
  load_af(h3s, lane, af);
  __syncthreads();  // all af reads done before phase 1 overwrites h3s

  // ---- phase 1: 32x512 = a3[32x128] @ W3 into LDS; ring prefetch depth 3 ----
  {
    f32x4 acc0 = {0, 0, 0, 0}, acc1 = {0, 0, 0, 0};
    half8 bq[4];
#pragma unroll
    for (int p = 0; p < 3; p++)
      bq[p] = *(const half8*)&W3p[((ll64)(wave * 32 + p) * 64 + lane) * 8];
#pragma unroll 4
    for (int t = 0; t < 32; t++) {
      if (t + 3 < 32)
        bq[(t + 3) & 3] = *(const half8*)&W3p[((ll64)(wave * 32 + t + 3) * 64 + lane) * 8];
      half8 bcur = bq[t & 3];
      int kb = t & 3;
      acc0 = __builtin_amdgcn_mfma_f32_16x16x32_f16(af[0][kb], bcur, acc0, 0, 0, 0);
      acc1 = __builtin_amdgcn_mfma_f32_16x16x32_f16(af[1][kb], bcur, acc1, 0, 0, 0);
      if (kb == 3) {
        int nt = wave * 8 + (t >> 2);
        int col = nt * 16 + l16;
        float bv = b3[col];
#pragma unroll
        for (int r = 0; r < 4; r++) {
          int row0l = quad * 4 + r;
          float v0 = fmaxf(acc0[r] + bv, 0.0f);
          float v1 = fmaxf(acc1[r] + bv, 0.0f);
          int oct0 = (col >> 3) ^ (row0l & 7);
          h3s[row0l * 512 + oct0 * 8 + (col & 7)] = __half_as_ushort(__float2half(v0));
          int row1l = 16 + row0l;
          int oct1 = (col >> 3) ^ (row1l & 7);
          h3s[row1l * 512 + oct1 * 8 + (col & 7)] = __half_as_ushort(__float2half(v1));
        }
        acc0 = (f32x4){0, 0, 0, 0};
        acc1 = (f32x4){0, 0, 0, 0};
      }
    }
  }
  __syncthreads();

  // ---- phase 2: h3s @ Wi (K=512) + fold Wc; ring prefetch depth 3 ----
  float acc3[2][4][3] = {};
  {
    f32x4 acc0 = {0, 0, 0, 0}, acc1 = {0, 0, 0, 0};
    half8 bq[4];
#pragma unroll
    for (int p = 0; p < 3; p++)
      bq[p] = *(const half8*)&Wip[((ll64)(wave * 128 + p) * 64 + lane) * 8];
    int r0l = l16, r1l = 16 + l16;
    int sw0 = r0l & 7;
#pragma unroll 4
    for (int t = 0; t < 128; t++) {
      if (t + 3 < 128)
        bq[(t + 3) & 3] = *(const half8*)&Wip[((ll64)(wave * 128 + t + 3) * 64 + lane) * 8];
      half8 bcur = bq[t & 3];
      int kb = t & 15;
      int oct = ((kb * 4 + quad) ^ sw0);
      half8 a0 = *(const half8*)&h3s[r0l * 512 + oct * 8];
      half8 a1 = *(const half8*)&h3s[r1l * 512 + oct * 8];
      acc0 = __builtin_amdgcn_mfma_f32_16x16x32_f16(a0, bcur, acc0, 0, 0, 0);
      acc1 = __builtin_amdgcn_mfma_f32_16x16x32_f16(a1, bcur, acc1, 0, 0, 0);
      if (kb == 15) {
        int nt = wave * 8 + (t >> 4);
        int col = nt * 16 + l16;
        float bv = bi[col];
        float w0 = Wc[col * 3 + 0], w1 = Wc[col * 3 + 1], w2 = Wc[col * 3 + 2];
#pragma unroll
        for (int r = 0; r < 4; r++) {
          float v0 = fmaxf(acc0[r] + bv, 0.0f);
          float v1 = fmaxf(acc1[r] + bv, 0.0f);
          acc3[0][r][0] += v0 * w0; acc3[0][r][1] += v0 * w1; acc3[0][r][2] += v0 * w2;
          acc3[1][r][0] += v1 * w0; acc3[1][r][1] += v1 * w1; acc3[1][r][2] += v1 * w2;
        }
        acc0 = (f32x4){0, 0, 0, 0};
        acc1 = (f32x4){0, 0, 0, 0};
      }
    }
  }
#pragma unroll
  for (int rt = 0; rt < 2; rt++)
#pragma unroll
    for (int r = 0; r < 4; r++)
#pragma unroll
      for (int c = 0; c < 3; c++) {
        float v = acc3[rt][r][c];
        v += __shfl_xor(v, 1);
        v += __shfl_xor(v, 2);
        v += __shfl_xor(v, 4);
        v += __shfl_xor(v, 8);
        acc3[rt][r][c] = v;
      }
  if (l16 == 0) {
#pragma unroll
    for (int rt = 0; rt < 2; rt++)
#pragma unroll
      for (int r = 0; r < 4; r++)
#pragma unroll
        for (int c = 0; c < 3; c++)
          sRed[wave][rt * 16 + quad * 4 + r][c] = acc3[rt][r][c];
  }
  __syncthreads();
  if (tid < 96) {
    int row = tid / 3, c = tid % 3;
    out[(ll64)(row0 + row) * 3 + c] = sRed[0][row][c] + sRed[1][row][c] +
                                      sRed[2][row][c] + sRed[3][row][c] + bc[c];
  }
}

// ---------------- launcher ----------------
extern "C" void kernel_launch(void* const* d_in, const int* in_sizes, int n_in,
                              void* d_out, int out_size, void* d_ws, size_t ws_size,
                              hipStream_t stream) {
  const float* x  = (const float*)d_in[0];
  const void*  ei = d_in[1];
  const float* W1 = (const float*)d_in[2];
  const float* b1 = (const float*)d_in[3];
  const float* W2 = (const float*)d_in[4];
  const float* b2 = (const float*)d_in[5];
  const float* W3 = (const float*)d_in[6];
  const float* b3 = (const float*)d_in[7];
  const float* Wi = (const float*)d_in[8];
  const float* bi = (const float*)d_in[9];
  const float* Wc = (const float*)d_in[10];
  const float* bc = (const float*)d_in[11];
  float* out = (float*)d_out;

  char* ws = (char*)d_ws;
  const ll64 KB = 1ll << 10, MB = 1ll << 20;
  float* dinv  = (float*)(ws + 0);                 // 400 KB
  int*   offs  = (int*)(ws + 512 * KB);            // 400 KB (NN+1)
  int*   total = (int*)(ws + 1 * MB + 64 * KB);    // 1.6 KB
  int*   bbase = (int*)(ws + 1 * MB + 128 * KB);   // 1.6 KB
  int*   tbl   = (int*)(ws + 1 * MB + 192 * KB);   // 800 KB -> ends ~2 MB
  uint32* binned = (uint32*)(ws + 2 * MB);         // 12.8 MB -> 14.8
  int*   csr   = (int*)(ws + 15 * MB);             // 12.8 MB -> 27.8
  u16* pW1 = (u16*)(ws + 28 * MB);                 // 32 KB
  u16* pW2 = (u16*)(ws + 28 * MB + 64 * KB);       // 32 KB
  u16* pW3 = (u16*)(ws + 28 * MB + 128 * KB);      // 128 KB
  u16* pWi = (u16*)(ws + 28 * MB + 512 * KB);      // 512 KB
  u16* xh   = (u16*)(ws + 29 * MB);                // 25.6 MB -> 54.6
  u16* bufA = (u16*)(ws + 55 * MB);                // 25.6 MB -> 80.6
  u16* bufB = (u16*)(ws + 81 * MB);                // 25.6 MB -> 106.6

  const int TB = 256;
  k_binB<<<NBLK, TB, 0, stream>>>(ei, tbl);
  k_binC1<<<NB, NBLK, 0, stream>>>(tbl, total);
  k_binC2<<<1, 512, 0, stream>>>(total, bbase, offs);
  k_binD<<<NBLK, TB, 0, stream>>>(ei, tbl, bbase, binned);
  k_binE<<<NB, TB, 0, stream>>>(binned, bbase, total, offs, dinv, csr);
  // pack weights + convert x to dinv-prescaled fp16 (after binE: dinv ready)
  k_packhalf<<<(360448 + NN * 32 + TB - 1) / TB, TB, 0, stream>>>(
      W1, W2, W3, Wi, pW1, pW2, pW3, pWi, (const float4*)x, (ushort4*)xh, dinv);

  const int NB32 = NN / 32;  // 3125

  // layer 1: fused agg + GEMM128 (xh -> bufB)
  k_fusedL<<<NB32, TB, 0, stream>>>(xh, csr, offs, dinv, pW1, b1, bufB);
  // layer 2: fused agg + GEMM128 (bufB -> bufA)
  k_fusedL<<<NB32, TB, 0, stream>>>(bufB, csr, offs, dinv, pW2, b2, bufA);
  // layer 3: fused agg + GEMM512 + MLP head (bufA -> out)
  k_tail32f<<<NB32, TB, 0, stream>>>(bufA, csr, offs, dinv, pW3, b3, pWi, bi,
                                     Wc, bc, out, NN);
}